// Round 11
// baseline (944.746 us; speedup 1.0000x reference)
//
#include <hip/hip_runtime.h>
#include <hip/hip_bf16.h>
#include <cstdio>

// BlockAxialUp on MI355X, round 11: 2 blocks/CU via LDS diet (160KB -> 64KB).
//  - Xs staging dropped: production reads X direct from global (L1/L2-hot);
//    dir-0 reads a transposed copy xuT (written by upsample) so both dirs
//    read contiguous 512B token rows.
//  - V production phased AFTER S: V^T overwrites Kb (K dead); P overwrites
//    own Qb rows; O overwrites own P rows. LDS = Qb+Kb = 64KB.
//  - __launch_bounds__(512,4): 2 blocks/CU, 4 waves/SIMD, VGPR cap 128.
//  - all MFMA fragment mappings identical to round 10.
//
// ws layout (bytes):
//   0         wqkvT_h bf16 [768][256] (q 0:256, k 256:512, v 512:768)
//   393216    wqkvT_w
//   786432    woT_h  bf16 [256][256]
//   917504    woT_w
//   1048576   convT  bf16 [128][640]
//   1245184   xu     bf16 [65536][256]   (token = b,h,w)
//   34799616  ytmp   f32  [65536][128]
//   68354048  partial f32 [512][128][2]
//   68878336  stats  f32  [128][2]
//   68879360  accb1  bf16 [65536][256]
//   102433792 xuT    bf16 [65536][256]   (token = b,w,h)  -> end 135988224
// accb0 (dir-0) lives in d_out; final f32 output overwrites it.

typedef short bf16x8 __attribute__((ext_vector_type(8)));
typedef short bf16x4 __attribute__((ext_vector_type(4)));
typedef float f32x4 __attribute__((ext_vector_type(4)));

#define MFMA16(a, b, c) __builtin_amdgcn_mfma_f32_16x16x32_bf16((a), (b), (c), 0, 0, 0)

__device__ __forceinline__ short f2bf(float v) {
  __hip_bfloat16 h = __float2bfloat16(v);
  union { __hip_bfloat16 h; short s; } u; u.h = h; return u.s;
}
__device__ __forceinline__ float bf2f(short s) {
  return __uint_as_float(((unsigned int)(unsigned short)s) << 16);
}
// XOR swizzle, granule = 8 shorts (16 B); flips col bits 3-5 only.
__device__ __forceinline__ int swz(int row, int col) {
  return col ^ ((row & 7) << 3);
}

// ---------------- fused weight prep: dst[n][k] = bf16(src[k][n]) ------------
struct WtAll {
  const float* src[7];
  short* dst[7];
  int K[7], N[7], tile0[7];
};

__global__ __launch_bounds__(256) void k_wt_all(WtAll P) {
  const int bid = blockIdx.x;
  int i = 0;
#pragma unroll
  for (int j = 1; j < 7; j++) if (bid >= P.tile0[j]) i = j;
  const float* src = P.src[i];
  short* dst = P.dst[i];
  const int K = P.K[i], N = P.N[i];
  const int local = bid - P.tile0[i];
  const int ktiles = K >> 5;
  const int nt = local / ktiles, kt = local - nt * ktiles;
  const int k0 = kt * 32, n0 = nt * 32;
  __shared__ float tile[32][33];
  const int tx = threadIdx.x & 31, ty = threadIdx.x >> 5;
#pragma unroll
  for (int r = 0; r < 4; r++)
    tile[ty + r * 8][tx] = src[(size_t)(k0 + ty + r * 8) * N + n0 + tx];
  __syncthreads();
#pragma unroll
  for (int r = 0; r < 4; r++)
    dst[(size_t)(n0 + ty + r * 8) * K + k0 + tx] = f2bf(tile[tx][ty + r * 8]);
}

// ---------------- upsample 2x bilinear align_corners; writes xu AND xuT -----
__global__ __launch_bounds__(256) void k_upsample(const float* __restrict__ x,
                                                  short* __restrict__ xu,
                                                  short* __restrict__ xuT) {
  __shared__ float ldsV[64][65];
  const int bh = blockIdx.x, z = blockIdx.y;
  const int b = bh >> 7, h = bh & 127;
  const float chf = h * (63.0f / 127.0f);
  int i0 = (int)chf; if (i0 > 62) i0 = 62;
  const float wh = chf - (float)i0;
  const int t = threadIdx.x;
  const int cbase = z * 64;
  const float* xb = x + ((size_t)(b * 256 + cbase) * 64 + i0) * 64;
#pragma unroll
  for (int p = 0; p < 16; p++) {
    const int li = p * 256 + t;
    const int c = li >> 6, w = li & 63;
    const float* px = xb + (size_t)c * 4096 + w;
    const float v0 = px[0], v1 = px[64];
    ldsV[c][w] = v0 * (1.f - wh) + v1 * wh;
  }
  __syncthreads();
  const int cg = t & 7, wi = t >> 3;
  short* xout = xu + (size_t)(bh * 128) * 256 + cbase + cg * 8;
  short* xoutT = xuT + ((size_t)b * 16384 + h) * 256 + cbase + cg * 8;
#pragma unroll
  for (int p = 0; p < 4; p++) {
    const int w = p * 32 + wi;
    const float cwf = w * (63.0f / 127.0f);
    int j0 = (int)cwf; if (j0 > 62) j0 = 62;
    const float ww = cwf - (float)j0;
    bf16x8 o;
#pragma unroll
    for (int u = 0; u < 8; u++) {
      const float v0 = ldsV[cg * 8 + u][j0], v1 = ldsV[cg * 8 + u][j0 + 1];
      o[u] = f2bf(v0 * (1.f - ww) + v1 * ww);
    }
    *(bf16x8*)(xout + (size_t)w * 256) = o;
    *(bf16x8*)(xoutT + (size_t)w * 128 * 256) = o;
  }
}

// ---------------- fused QKV + attention + proj (64KB LDS, phased) -----------
// grid (512, 2): blockIdx.x = sequence, blockIdx.y = dir. 512 thr = 8 waves.
// LDS: Qb (Q -> P -> O) 32K + Kb (K -> V^T) 32K = 64KB -> 2 blocks/CU.
__global__ __launch_bounds__(512, 4) void k_fused(const short* __restrict__ xu,
                                                  const short* __restrict__ xuT,
                                                  const short* __restrict__ wqkvT0,
                                                  const short* __restrict__ woT0,
                                                  const float* __restrict__ wob0,
                                                  const float* __restrict__ wob1,
                                                  short* __restrict__ accb0,
                                                  short* __restrict__ accb1) {
  __shared__ __align__(16) short Qb[128][128];   // Q, then P, then O
  __shared__ __align__(16) short Kb[128][128];   // K, then V^T

  const int dir = blockIdx.y;
  const short* wqkvT = wqkvT0 + (size_t)dir * 196608;
  const short* woT   = woT0 + (size_t)dir * 65536;
  const float* wob   = dir ? wob1 : wob0;
  short* accb        = dir ? accb1 : accb0;

  const int s = blockIdx.x;
  const int b = s >> 7, pos = s & 127;
  const int tok0 = b * 16384 + (dir ? pos * 128 : pos);   // OUTPUT indexing
  const int tstep = dir ? 1 : 128;
  // INPUT: both dirs read contiguous token rows (dir0 via transposed copy)
  const short* Xb = (dir ? xu : xuT) + ((size_t)b * 16384 + (size_t)pos * 128) * 256;

  const int tid = threadIdx.x;
  const int lane = tid & 63, wid = tid >> 6;
  const int lr = lane & 15, kb = lane >> 4;
  const int ct = wid * 16;                    // wave's chan/token tile base
  const float scale = 0.08838834764831845f;  // 128^-0.5

  f32x4 accp[2][8];
#pragma unroll
  for (int i = 0; i < 2; i++)
#pragma unroll
    for (int j = 0; j < 8; j++) accp[i][j] = (f32x4){0.f, 0.f, 0.f, 0.f};

  for (int h = 0; h < 2; h++) {
    // ---- phase 1: Q,K production (X from global, chan slice ct..ct+15) ----
    {
      const short* wqb = wqkvT + (size_t)(h * 128 + ct + lr) * 256 + kb * 8;
      const short* wkb = wqkvT + (size_t)(256 + h * 128 + ct + lr) * 256 + kb * 8;
      bf16x8 wq[8], wk[8];
#pragma unroll
      for (int ks = 0; ks < 8; ks++) {
        wq[ks] = *(const bf16x8*)(wqb + ks * 32);
        wk[ks] = *(const bf16x8*)(wkb + ks * 32);
      }
#pragma unroll
      for (int nt = 0; nt < 8; nt++) {
        const short* xr = Xb + (size_t)(nt * 16 + lr) * 256 + kb * 8;
        f32x4 dq = (f32x4){0.f, 0.f, 0.f, 0.f};
        f32x4 dk = (f32x4){0.f, 0.f, 0.f, 0.f};
#pragma unroll
        for (int ks = 0; ks < 8; ks++) {
          bf16x8 xf = *(const bf16x8*)(xr + ks * 32);
          dq = MFMA16(wq[ks], xf, dq);   // D[chan][token]
          dk = MFMA16(wk[ks], xf, dk);   // D[chan][token]
        }
        const int trow = nt * 16 + lr, cc = ct + kb * 4;
        bf16x4 pq = {f2bf(dq[0]), f2bf(dq[1]), f2bf(dq[2]), f2bf(dq[3])};
        bf16x4 pk = {f2bf(dk[0]), f2bf(dk[1]), f2bf(dk[2]), f2bf(dk[3])};
        *(bf16x4*)&Qb[trow][swz(trow, cc)] = pq;
        *(bf16x4*)&Kb[trow][swz(trow, cc)] = pk;
      }
    }
    __syncthreads();  // (1) Q,K visible to all waves

    // ---- phase 2: S^T = K Q^T (lane owns q-token ct+lr) ----
    f32x4 s8[8];
#pragma unroll
    for (int i = 0; i < 8; i++) s8[i] = (f32x4){0.f, 0.f, 0.f, 0.f};
    const int qrow = ct + lr;
#pragma unroll
    for (int ks = 0; ks < 4; ks++) {
      bf16x8 aq = *(const bf16x8*)&Qb[qrow][swz(qrow, kb * 8 + ks * 32)];
#pragma unroll
      for (int nj = 0; nj < 8; nj++) {
        const int krow = nj * 16 + lr;
        bf16x8 bk = *(const bf16x8*)&Kb[krow][swz(krow, kb * 8 + ks * 32)];
        s8[nj] = MFMA16(bk, aq, s8[nj]);   // D[k-token][q-token]
      }
    }
    // per-lane softmax (xor 16, 32); P overwrites OWN Qb row (wave-private)
    {
      float m = s8[0][0];
#pragma unroll
      for (int nj = 0; nj < 8; nj++)
#pragma unroll
        for (int r = 0; r < 4; r++) m = fmaxf(m, s8[nj][r]);
      m = fmaxf(m, __shfl_xor(m, 16));
      m = fmaxf(m, __shfl_xor(m, 32));
      float sum = 0.f;
#pragma unroll
      for (int nj = 0; nj < 8; nj++)
#pragma unroll
        for (int r = 0; r < 4; r++) {
          s8[nj][r] = __expf((s8[nj][r] - m) * scale);
          sum += s8[nj][r];
        }
      sum += __shfl_xor(sum, 16);
      sum += __shfl_xor(sum, 32);
      const float inv = 1.f / sum;
#pragma unroll
      for (int nj = 0; nj < 8; nj++) {
        bf16x4 pp = {f2bf(s8[nj][0] * inv), f2bf(s8[nj][1] * inv),
                     f2bf(s8[nj][2] * inv), f2bf(s8[nj][3] * inv)};
        *(bf16x4*)&Qb[qrow][swz(qrow, nj * 16 + kb * 4)] = pp;
      }
    }
    __syncthreads();  // (2) all S reads of Kb done -> V^T may overwrite

    // ---- phase 3: V^T production into Kb (swapped: D[token][chan]) ----
    {
      const short* wvb = wqkvT + (size_t)(512 + h * 128 + ct + lr) * 256 + kb * 8;
      bf16x8 wv[8];
#pragma unroll
      for (int ks = 0; ks < 8; ks++) wv[ks] = *(const bf16x8*)(wvb + ks * 32);
#pragma unroll
      for (int nt = 0; nt < 8; nt++) {
        const short* xr = Xb + (size_t)(nt * 16 + lr) * 256 + kb * 8;
        f32x4 dv = (f32x4){0.f, 0.f, 0.f, 0.f};
#pragma unroll
        for (int ks = 0; ks < 8; ks++) {
          bf16x8 xf = *(const bf16x8*)(xr + ks * 32);
          dv = MFMA16(xf, wv[ks], dv);   // D[token][chan]
        }
        const int vrow = ct + lr;       // chan row of V^T
        bf16x4 pv = {f2bf(dv[0]), f2bf(dv[1]), f2bf(dv[2]), f2bf(dv[3])};
        *(bf16x4*)&Kb[vrow][swz(vrow, nt * 16 + kb * 4)] = pv;
      }
    }
    __syncthreads();  // (3) V^T visible

    // ---- phase 4: O = P V (P own Qb row; Vt all Kb rows) ----
    f32x4 o8[8];
#pragma unroll
    for (int i = 0; i < 8; i++) o8[i] = (f32x4){0.f, 0.f, 0.f, 0.f};
#pragma unroll
    for (int ks = 0; ks < 4; ks++) {
      bf16x8 bp = *(const bf16x8*)&Qb[qrow][swz(qrow, kb * 8 + ks * 32)];
#pragma unroll
      for (int mi = 0; mi < 8; mi++) {
        const int vrow = mi * 16 + lr;
        bf16x8 av = *(const bf16x8*)&Kb[vrow][swz(vrow, kb * 8 + ks * 32)];
        o8[mi] = MFMA16(av, bp, o8[mi]);   // D[chan][q-token]
      }
    }
    // O overwrites OWN P row (wave-private; same-wave LDS order is safe)
#pragma unroll
    for (int mi = 0; mi < 8; mi++) {
      const int cc = mi * 16 + kb * 4;
      bf16x4 po = {f2bf(o8[mi][0]), f2bf(o8[mi][1]), f2bf(o8[mi][2]), f2bf(o8[mi][3])};
      *(bf16x4*)&Qb[qrow][swz(qrow, cc)] = po;
    }
    __syncthreads();  // (4) O complete for all waves

    // ---- phase 5: proj (out-chans [wid*32, +32), all tokens; O from Qb) ----
    {
      const short* w0 = woT + (size_t)(wid * 32 + lr) * 256 + h * 128 + kb * 8;
      const short* w1 = woT + (size_t)(wid * 32 + 16 + lr) * 256 + h * 128 + kb * 8;
      bf16x8 wa[4], wb2[4];
#pragma unroll
      for (int ks = 0; ks < 4; ks++) {
        wa[ks]  = *(const bf16x8*)(w0 + ks * 32);
        wb2[ks] = *(const bf16x8*)(w1 + ks * 32);
      }
#pragma unroll
      for (int nt = 0; nt < 8; nt++) {
        const int trow = nt * 16 + lr;
#pragma unroll
        for (int ks = 0; ks < 4; ks++) {
          bf16x8 bo = *(const bf16x8*)&Qb[trow][swz(trow, kb * 8 + ks * 32)];
          accp[0][nt] = MFMA16(wa[ks], bo, accp[0][nt]);
          accp[1][nt] = MFMA16(wb2[ks], bo, accp[1][nt]);
        }
      }
    }
    if (h == 0) __syncthreads();  // (5) proj reads done before next head prod
  }

  // ---- accb write: token = nt*16+lr, outc = wid*32 + mi2*16 + kb*4 + r ----
#pragma unroll
  for (int mi2 = 0; mi2 < 2; mi2++) {
    const int outc = wid * 32 + mi2 * 16 + kb * 4;
    const float b0 = wob[outc], b1 = wob[outc + 1];
    const float b2 = wob[outc + 2], b3 = wob[outc + 3];
#pragma unroll
    for (int nt = 0; nt < 8; nt++) {
      const int token = tok0 + (nt * 16 + lr) * tstep;
      bf16x4 pv = {f2bf(accp[mi2][nt][0] + b0), f2bf(accp[mi2][nt][1] + b1),
                   f2bf(accp[mi2][nt][2] + b2), f2bf(accp[mi2][nt][3] + b3)};
      *(bf16x4*)(accb + (size_t)token * 256 + outc) = pv;
    }
  }
}

// ---- conv1x1: [relu(a0+a1)|xu|res] @ convT^T -> relu -> ytmp(f32) + BN partials
__global__ __launch_bounds__(256) void k_gemm_conv(const short* __restrict__ accb0,
                                                   const short* __restrict__ accb1,
                                                   const short* __restrict__ xu,
                                                   const float* __restrict__ res,
                                                   const short* __restrict__ Bt,
                                                   float* __restrict__ ytmp,
                                                   float* __restrict__ partial) {
  __shared__ float redS[2][128], redS2[2][128];
  const int tid = threadIdx.x;
  const int lane = tid & 63, wid = tid >> 6;
  const int lr = lane & 15, kb = lane >> 4;
  const int wr = wid >> 1, wc = wid & 1;
  const int m0 = blockIdx.y * 128;
  f32x4 acc[4][4];
#pragma unroll
  for (int i = 0; i < 4; i++)
#pragma unroll
    for (int j = 0; j < 4; j++) acc[i][j] = (f32x4){0.f, 0.f, 0.f, 0.f};
  const short* arow0 = accb0 + (size_t)(m0 + wr * 64 + lr) * 256 + kb * 8;
  const short* arow1 = accb1 + (size_t)(m0 + wr * 64 + lr) * 256 + kb * 8;
  const short* arow2 = xu + (size_t)(m0 + wr * 64 + lr) * 256 + kb * 8;
  const short* brow = Bt + (size_t)(wc * 64 + lr) * 640 + kb * 8;
#pragma unroll
  for (int ks = 0; ks < 8; ks++) {
    bf16x8 a[4], b[4];
#pragma unroll
    for (int mi = 0; mi < 4; mi++) {
      bf16x8 t0 = *(const bf16x8*)(arow0 + (size_t)mi * 16 * 256 + ks * 32);
      bf16x8 t1 = *(const bf16x8*)(arow1 + (size_t)mi * 16 * 256 + ks * 32);
      bf16x8 tv;
#pragma unroll
      for (int u = 0; u < 8; u++) {
        float sv = bf2f(t0[u]) + bf2f(t1[u]);
        tv[u] = f2bf(fmaxf(sv, 0.f));
      }
      a[mi] = tv;
    }
#pragma unroll
    for (int nj = 0; nj < 4; nj++)
      b[nj] = *(const bf16x8*)(brow + (size_t)nj * 16 * 640 + ks * 32);
#pragma unroll
    for (int mi = 0; mi < 4; mi++)
#pragma unroll
      for (int nj = 0; nj < 4; nj++)
        acc[mi][nj] = MFMA16(a[mi], b[nj], acc[mi][nj]);
  }
#pragma unroll
  for (int ks = 8; ks < 16; ks++) {
    bf16x8 a[4], b[4];
#pragma unroll
    for (int mi = 0; mi < 4; mi++)
      a[mi] = *(const bf16x8*)(arow2 + (size_t)mi * 16 * 256 + (ks - 8) * 32);
#pragma unroll
    for (int nj = 0; nj < 4; nj++)
      b[nj] = *(const bf16x8*)(brow + (size_t)nj * 16 * 640 + ks * 32);
#pragma unroll
    for (int mi = 0; mi < 4; mi++)
#pragma unroll
      for (int nj = 0; nj < 4; nj++)
        acc[mi][nj] = MFMA16(a[mi], b[nj], acc[mi][nj]);
  }
  const int bC = (m0 >> 14) * 128;
  const int hh = (m0 >> 7) & 127;
#pragma unroll
  for (int ks = 16; ks < 20; ks++) {
    const int e0 = (ks - 16) * 32 + kb * 8;
    bf16x8 a[4], b[4];
#pragma unroll
    for (int mi = 0; mi < 4; mi++) {
      const int wl = wr * 64 + mi * 16 + lr;
      const float* rp = res + ((size_t)(bC + e0) * 128 + hh) * 128 + wl;
      bf16x8 tv;
#pragma unroll
      for (int u = 0; u < 8; u++) tv[u] = f2bf(rp[(size_t)u * 16384]);
      a[mi] = tv;
    }
#pragma unroll
    for (int nj = 0; nj < 4; nj++)
      b[nj] = *(const bf16x8*)(brow + (size_t)nj * 16 * 640 + ks * 32);
#pragma unroll
    for (int mi = 0; mi < 4; mi++)
#pragma unroll
      for (int nj = 0; nj < 4; nj++)
        acc[mi][nj] = MFMA16(a[mi], b[nj], acc[mi][nj]);
  }
  // epilogue: relu -> f32 ytmp + per-channel partial sums (exact f32)
#pragma unroll
  for (int nj = 0; nj < 4; nj++) {
    float s = 0.f, s2 = 0.f;
    const int c = wc * 64 + nj * 16 + lr;
#pragma unroll
    for (int mi = 0; mi < 4; mi++) {
      const int rbase = m0 + wr * 64 + mi * 16 + kb * 4;
#pragma unroll
      for (int r = 0; r < 4; r++) {
        const float yv = fmaxf(acc[mi][nj][r], 0.f);
        ytmp[(size_t)(rbase + r) * 128 + c] = yv;
        s += yv; s2 += yv * yv;
      }
    }
    s += __shfl_xor(s, 16);  s += __shfl_xor(s, 32);
    s2 += __shfl_xor(s2, 16); s2 += __shfl_xor(s2, 32);
    if (kb == 0) { redS[wr][c] = s; redS2[wr][c] = s2; }
  }
  __syncthreads();
  if (tid < 128) {
    partial[((size_t)blockIdx.y * 128 + tid) * 2]     = redS[0][tid] + redS[1][tid];
    partial[((size_t)blockIdx.y * 128 + tid) * 2 + 1] = redS2[0][tid] + redS2[1][tid];
  }
}

// ---------------- BN stats final reduce ----------------
__global__ __launch_bounds__(128) void k_bnstats2(const float* __restrict__ partial,
                                                  float* __restrict__ stats) {
  const int ch = threadIdx.x;
  float s = 0.f, s2 = 0.f;
  for (int i = 0; i < 512; i++) {
    s  += partial[(size_t)(i * 128 + ch) * 2];
    s2 += partial[(size_t)(i * 128 + ch) * 2 + 1];
  }
  const float mu = s * (1.f / 65536.f);
  const float var = s2 * (1.f / 65536.f) - mu * mu;
  stats[ch * 2] = mu;
  stats[ch * 2 + 1] = rsqrtf(var + 1e-5f);
}

// ---------------- BN apply + transpose to (B,E,H,W), coalesced writes -------
__global__ __launch_bounds__(256) void k_bnout(const float* __restrict__ y,
                                               const float* __restrict__ stats,
                                               const float* __restrict__ gamma,
                                               const float* __restrict__ beta,
                                               float* __restrict__ out) {
  const int bh = blockIdx.x;
  const int b = bh >> 7, h = bh & 127;
  const int w = threadIdx.x & 127, half = threadIdx.x >> 7;
  const float* yp = y + (size_t)(bh * 128 + w) * 128 + half * 64;
  float* op = out + ((size_t)(b * 128) << 14) + h * 128 + w;
#pragma unroll
  for (int e4 = 0; e4 < 16; e4++) {
    f32x4 v = *(const f32x4*)(yp + e4 * 4);
#pragma unroll
    for (int u = 0; u < 4; u++) {
      const int e = half * 64 + e4 * 4 + u;
      const float mu = stats[e * 2], rstd = stats[e * 2 + 1];
      op[(size_t)e << 14] = (v[u] - mu) * rstd * gamma[e] + beta[e];
    }
  }
}

// ---------------- launcher ----------------
extern "C" void kernel_launch(void* const* d_in, const int* in_sizes, int n_in,
                              void* d_out, int out_size, void* d_ws, size_t ws_size,
                              hipStream_t stream) {
  const float* x      = (const float*)d_in[0];
  const float* res    = (const float*)d_in[1];
  const float* wq_h   = (const float*)d_in[2];
  const float* wkv_h  = (const float*)d_in[3];
  const float* wo_h   = (const float*)d_in[4];
  const float* wob_h  = (const float*)d_in[5];
  const float* wq_w   = (const float*)d_in[6];
  const float* wkv_w  = (const float*)d_in[7];
  const float* wo_w   = (const float*)d_in[8];
  const float* wob_w  = (const float*)d_in[9];
  const float* conv_w = (const float*)d_in[10];
  const float* gamma  = (const float*)d_in[11];
  const float* beta   = (const float*)d_in[12];

  char* ws = (char*)d_ws;
  short* wqkvT[2] = {(short*)(ws + 0), (short*)(ws + 393216)};
  short* woT[2]   = {(short*)(ws + 786432), (short*)(ws + 917504)};
  short* convT    = (short*)(ws + 1048576);
  short* xu       = (short*)(ws + 1245184);
  float* ytmp     = (float*)(ws + 34799616);
  float* partial  = (float*)(ws + 68354048);
  float* stats    = (float*)(ws + 68878336);
  short* accb1    = (short*)(ws + 68879360);
  short* xuT      = (short*)(ws + 102433792);
  short* accb0    = (short*)d_out;             // dir-0 axial output in d_out
  float* out      = (float*)d_out;

  if (ws_size < 135988224ull)
    fprintf(stderr, "kernel_launch: ws_size %zu too small\n", ws_size);

  // fused weight prep: starts 0,64,192,256,384,448,512; total 592 tiles
  WtAll P;
  P.src[0] = wq_h;  P.dst[0] = wqkvT[0];          P.K[0] = 256; P.N[0] = 256; P.tile0[0] = 0;
  P.src[1] = wkv_h; P.dst[1] = wqkvT[0] + 65536;  P.K[1] = 256; P.N[1] = 512; P.tile0[1] = 64;
  P.src[2] = wq_w;  P.dst[2] = wqkvT[1];          P.K[2] = 256; P.N[2] = 256; P.tile0[2] = 192;
  P.src[3] = wkv_w; P.dst[3] = wqkvT[1] + 65536;  P.K[3] = 256; P.N[3] = 512; P.tile0[3] = 256;
  P.src[4] = wo_h;  P.dst[4] = woT[0];            P.K[4] = 256; P.N[4] = 256; P.tile0[4] = 384;
  P.src[5] = wo_w;  P.dst[5] = woT[1];            P.K[5] = 256; P.N[5] = 256; P.tile0[5] = 448;
  P.src[6] = conv_w;P.dst[6] = convT;             P.K[6] = 640; P.N[6] = 128; P.tile0[6] = 512;
  k_wt_all<<<592, 256, 0, stream>>>(P);

  k_upsample<<<dim3(512, 4), 256, 0, stream>>>(x, xu, xuT);

  k_fused<<<dim3(512, 2), 512, 0, stream>>>(xu, xuT, wqkvT[0], woT[0],
                                            wob_h, wob_w, accb0, accb1);

  k_gemm_conv<<<dim3(1, 512), 256, 0, stream>>>(accb0, accb1, xu, res, convT,
                                                ytmp, partial);
  k_bnstats2<<<1, 128, 0, stream>>>(partial, stats);
  k_bnout<<<512, 256, 0, stream>>>(ytmp, stats, gamma, beta, out);
}

// Round 12
// 548.464 us; speedup vs baseline: 1.7225x; 1.7225x over previous
//
#include <hip/hip_runtime.h>
#include <hip/hip_bf16.h>
#include <cstdio>

// BlockAxialUp on MI355X, round 12: round-10 body (proven (512,2), 124 VGPR,
// no spills) minus the 64KB Xs staging: production reads X direct from global
// (dir0 via transposed xuT written by upsample; dir1 via xu). LDS 160->96KB,
// removes ~40% of LDS-pipe ops. Launch bounds kept at (512,2) - rounds 8/9/11
// proved (.,4) forces a 64-VGPR cap and GB-scale scratch spills.
//
// ws layout (bytes):
//   0         wqkvT_h bf16 [768][256] (q 0:256, k 256:512, v 512:768)
//   393216    wqkvT_w
//   786432    woT_h  bf16 [256][256]
//   917504    woT_w
//   1048576   convT  bf16 [128][640]
//   1245184   xu     bf16 [65536][256]   (token = b,h,w)
//   34799616  ytmp   f32  [65536][128]
//   68354048  partial f32 [512][128][2]
//   68878336  stats  f32  [128][2]
//   68879360  accb1  bf16 [65536][256]
//   102433792 xuT    bf16 [65536][256]   (token = b,w,h)  -> end 135988224
// accb0 (dir-0) lives in d_out; final f32 output overwrites it.

typedef short bf16x8 __attribute__((ext_vector_type(8)));
typedef short bf16x4 __attribute__((ext_vector_type(4)));
typedef float f32x4 __attribute__((ext_vector_type(4)));

#define MFMA16(a, b, c) __builtin_amdgcn_mfma_f32_16x16x32_bf16((a), (b), (c), 0, 0, 0)

__device__ __forceinline__ short f2bf(float v) {
  __hip_bfloat16 h = __float2bfloat16(v);
  union { __hip_bfloat16 h; short s; } u; u.h = h; return u.s;
}
__device__ __forceinline__ float bf2f(short s) {
  return __uint_as_float(((unsigned int)(unsigned short)s) << 16);
}
// XOR swizzle, granule = 8 shorts (16 B); flips col bits 3-5 only.
__device__ __forceinline__ int swz(int row, int col) {
  return col ^ ((row & 7) << 3);
}

// ---------------- fused weight prep: dst[n][k] = bf16(src[k][n]) ------------
struct WtAll {
  const float* src[7];
  short* dst[7];
  int K[7], N[7], tile0[7];
};

__global__ __launch_bounds__(256) void k_wt_all(WtAll P) {
  const int bid = blockIdx.x;
  int i = 0;
#pragma unroll
  for (int j = 1; j < 7; j++) if (bid >= P.tile0[j]) i = j;
  const float* src = P.src[i];
  short* dst = P.dst[i];
  const int K = P.K[i], N = P.N[i];
  const int local = bid - P.tile0[i];
  const int ktiles = K >> 5;
  const int nt = local / ktiles, kt = local - nt * ktiles;
  const int k0 = kt * 32, n0 = nt * 32;
  __shared__ float tile[32][33];
  const int tx = threadIdx.x & 31, ty = threadIdx.x >> 5;
#pragma unroll
  for (int r = 0; r < 4; r++)
    tile[ty + r * 8][tx] = src[(size_t)(k0 + ty + r * 8) * N + n0 + tx];
  __syncthreads();
#pragma unroll
  for (int r = 0; r < 4; r++)
    dst[(size_t)(n0 + ty + r * 8) * K + k0 + tx] = f2bf(tile[tx][ty + r * 8]);
}

// ---------------- upsample 2x bilinear align_corners; writes xu AND xuT -----
__global__ __launch_bounds__(256) void k_upsample(const float* __restrict__ x,
                                                  short* __restrict__ xu,
                                                  short* __restrict__ xuT) {
  __shared__ float ldsV[64][65];
  const int bh = blockIdx.x, z = blockIdx.y;
  const int b = bh >> 7, h = bh & 127;
  const float chf = h * (63.0f / 127.0f);
  int i0 = (int)chf; if (i0 > 62) i0 = 62;
  const float wh = chf - (float)i0;
  const int t = threadIdx.x;
  const int cbase = z * 64;
  const float* xb = x + ((size_t)(b * 256 + cbase) * 64 + i0) * 64;
#pragma unroll
  for (int p = 0; p < 16; p++) {
    const int li = p * 256 + t;
    const int c = li >> 6, w = li & 63;
    const float* px = xb + (size_t)c * 4096 + w;
    const float v0 = px[0], v1 = px[64];
    ldsV[c][w] = v0 * (1.f - wh) + v1 * wh;
  }
  __syncthreads();
  const int cg = t & 7, wi = t >> 3;
  short* xout = xu + (size_t)(bh * 128) * 256 + cbase + cg * 8;
  short* xoutT = xuT + ((size_t)b * 16384 + h) * 256 + cbase + cg * 8;
#pragma unroll
  for (int p = 0; p < 4; p++) {
    const int w = p * 32 + wi;
    const float cwf = w * (63.0f / 127.0f);
    int j0 = (int)cwf; if (j0 > 62) j0 = 62;
    const float ww = cwf - (float)j0;
    bf16x8 o;
#pragma unroll
    for (int u = 0; u < 8; u++) {
      const float v0 = ldsV[cg * 8 + u][j0], v1 = ldsV[cg * 8 + u][j0 + 1];
      o[u] = f2bf(v0 * (1.f - ww) + v1 * ww);
    }
    *(bf16x8*)(xout + (size_t)w * 256) = o;
    *(bf16x8*)(xoutT + (size_t)w * 128 * 256) = o;
  }
}

// ---------------- fused QKV + attention + proj (round-10 body, no Xs) -------
// grid (512, 2): blockIdx.x = sequence, blockIdx.y = dir. 512 thr = 8 waves.
// LDS: Qb (Q->P) 32K + Kb (K->O) 32K + Vtb 32K = 96 KB. X read from global.
__global__ __launch_bounds__(512, 2) void k_fused(const short* __restrict__ xu,
                                                  const short* __restrict__ xuT,
                                                  const short* __restrict__ wqkvT0,
                                                  const short* __restrict__ woT0,
                                                  const float* __restrict__ wob0,
                                                  const float* __restrict__ wob1,
                                                  short* __restrict__ accb0,
                                                  short* __restrict__ accb1) {
  __shared__ __align__(16) short Qb[128][128];   // Q, then P
  __shared__ __align__(16) short Kb[128][128];   // K, then O
  __shared__ __align__(16) short Vtb[128][128];  // V^T

  const int dir = blockIdx.y;
  const short* wqkvT = wqkvT0 + (size_t)dir * 196608;
  const short* woT   = woT0 + (size_t)dir * 65536;
  const float* wob   = dir ? wob1 : wob0;
  short* accb        = dir ? accb1 : accb0;

  const int s = blockIdx.x;
  const int b = s >> 7, pos = s & 127;
  const int tok0 = b * 16384 + (dir ? pos * 128 : pos);   // OUTPUT indexing
  const int tstep = dir ? 1 : 128;
  // INPUT: both dirs read contiguous token rows (dir0 via transposed copy)
  const short* Xb = (dir ? xu : xuT) + ((size_t)b * 16384 + (size_t)pos * 128) * 256;

  const int tid = threadIdx.x;
  const int lane = tid & 63, wid = tid >> 6;
  const int lr = lane & 15, kb = lane >> 4;
  const int ct = wid * 16;                    // wave's chan/token tile base
  const float scale = 0.08838834764831845f;  // 128^-0.5

  f32x4 accp[2][8];
#pragma unroll
  for (int i = 0; i < 2; i++)
#pragma unroll
    for (int j = 0; j < 8; j++) accp[i][j] = (f32x4){0.f, 0.f, 0.f, 0.f};

  for (int h = 0; h < 2; h++) {
    // weight fragments for this head (L1/L2-hot, identical across blocks)
    const short* wqb = wqkvT + (size_t)(h * 128 + ct + lr) * 256 + kb * 8;
    const short* wkb = wqkvT + (size_t)(256 + h * 128 + ct + lr) * 256 + kb * 8;
    const short* wvb = wqkvT + (size_t)(512 + h * 128 + ct + lr) * 256 + kb * 8;
    bf16x8 wq[8], wk[8], wv[8];
#pragma unroll
    for (int ks = 0; ks < 8; ks++) {
      wq[ks] = *(const bf16x8*)(wqb + ks * 32);
      wk[ks] = *(const bf16x8*)(wkb + ks * 32);
      wv[ks] = *(const bf16x8*)(wvb + ks * 32);
    }

    __syncthreads();  // A: prev head's proj reads of Kb done (h=1); no-op h=0

    // ---- merged Q/K/V production: X from GLOBAL (contiguous rows) ----
#pragma unroll
    for (int nt = 0; nt < 8; nt++) {
      const short* xr = Xb + (size_t)(nt * 16 + lr) * 256 + kb * 8;
      f32x4 dq = (f32x4){0.f, 0.f, 0.f, 0.f};
      f32x4 dk = (f32x4){0.f, 0.f, 0.f, 0.f};
      f32x4 dv = (f32x4){0.f, 0.f, 0.f, 0.f};
#pragma unroll
      for (int ks = 0; ks < 8; ks++) {
        bf16x8 xf = *(const bf16x8*)(xr + ks * 32);
        dq = MFMA16(wq[ks], xf, dq);   // D[chan][token]
        dk = MFMA16(wk[ks], xf, dk);   // D[chan][token]
        dv = MFMA16(xf, wv[ks], dv);   // swapped: D[token][chan]
      }
      const int trow = nt * 16 + lr, cc = ct + kb * 4;
      bf16x4 pq = {f2bf(dq[0]), f2bf(dq[1]), f2bf(dq[2]), f2bf(dq[3])};
      bf16x4 pk = {f2bf(dk[0]), f2bf(dk[1]), f2bf(dk[2]), f2bf(dk[3])};
      *(bf16x4*)&Qb[trow][swz(trow, cc)] = pq;
      *(bf16x4*)&Kb[trow][swz(trow, cc)] = pk;
      const int vrow = ct + lr;
      bf16x4 pv = {f2bf(dv[0]), f2bf(dv[1]), f2bf(dv[2]), f2bf(dv[3])};
      *(bf16x4*)&Vtb[vrow][swz(vrow, nt * 16 + kb * 4)] = pv;
    }

    __syncthreads();  // B: Q/K/Vt visible to all waves

    // ---- S^T = K Q^T : lane owns q-token ct+lr ----
    f32x4 s8[8];
#pragma unroll
    for (int i = 0; i < 8; i++) s8[i] = (f32x4){0.f, 0.f, 0.f, 0.f};
    const int qrow = ct + lr;
#pragma unroll
    for (int ks = 0; ks < 4; ks++) {
      bf16x8 aq = *(const bf16x8*)&Qb[qrow][swz(qrow, kb * 8 + ks * 32)];
#pragma unroll
      for (int nj = 0; nj < 8; nj++) {
        const int krow = nj * 16 + lr;
        bf16x8 bk = *(const bf16x8*)&Kb[krow][swz(krow, kb * 8 + ks * 32)];
        s8[nj] = MFMA16(bk, aq, s8[nj]);   // D[k-token][q-token]
      }
    }
    // ---- per-lane softmax (xor 16, 32); P overwrites own Qb row ----
    {
      float m = s8[0][0];
#pragma unroll
      for (int nj = 0; nj < 8; nj++)
#pragma unroll
        for (int r = 0; r < 4; r++) m = fmaxf(m, s8[nj][r]);
      m = fmaxf(m, __shfl_xor(m, 16));
      m = fmaxf(m, __shfl_xor(m, 32));
      float sum = 0.f;
#pragma unroll
      for (int nj = 0; nj < 8; nj++)
#pragma unroll
        for (int r = 0; r < 4; r++) {
          s8[nj][r] = __expf((s8[nj][r] - m) * scale);
          sum += s8[nj][r];
        }
      sum += __shfl_xor(sum, 16);
      sum += __shfl_xor(sum, 32);
      const float inv = 1.f / sum;
#pragma unroll
      for (int nj = 0; nj < 8; nj++) {
        bf16x4 pp = {f2bf(s8[nj][0] * inv), f2bf(s8[nj][1] * inv),
                     f2bf(s8[nj][2] * inv), f2bf(s8[nj][3] * inv)};
        *(bf16x4*)&Qb[qrow][swz(qrow, nj * 16 + kb * 4)] = pp;
      }
    }

    // ---- O = P V : lane reads own P row (in-wave dep), all Vtb rows ----
    f32x4 o8[8];
#pragma unroll
    for (int i = 0; i < 8; i++) o8[i] = (f32x4){0.f, 0.f, 0.f, 0.f};
#pragma unroll
    for (int ks = 0; ks < 4; ks++) {
      bf16x8 bp = *(const bf16x8*)&Qb[qrow][swz(qrow, kb * 8 + ks * 32)];
#pragma unroll
      for (int mi = 0; mi < 8; mi++) {
        const int vrow = mi * 16 + lr;
        bf16x8 av = *(const bf16x8*)&Vtb[vrow][swz(vrow, kb * 8 + ks * 32)];
        o8[mi] = MFMA16(av, bp, o8[mi]);   // D[chan][q-token]
      }
    }

    __syncthreads();  // C: all waves' S reads of Kb done; O may overwrite

#pragma unroll
    for (int mi = 0; mi < 8; mi++) {
      const int cc = mi * 16 + kb * 4;
      bf16x4 po = {f2bf(o8[mi][0]), f2bf(o8[mi][1]), f2bf(o8[mi][2]), f2bf(o8[mi][3])};
      *(bf16x4*)&Kb[qrow][swz(qrow, cc)] = po;
    }

    __syncthreads();  // D: O complete for all waves

    // ---- proj: out-chans [wid*32, wid*32+32), all tokens ----
    {
      const short* w0 = woT + (size_t)(wid * 32 + lr) * 256 + h * 128 + kb * 8;
      const short* w1 = woT + (size_t)(wid * 32 + 16 + lr) * 256 + h * 128 + kb * 8;
      bf16x8 wa[4], wb2[4];
#pragma unroll
      for (int ks = 0; ks < 4; ks++) {
        wa[ks]  = *(const bf16x8*)(w0 + ks * 32);
        wb2[ks] = *(const bf16x8*)(w1 + ks * 32);
      }
#pragma unroll
      for (int nt = 0; nt < 8; nt++) {
        const int trow = nt * 16 + lr;
#pragma unroll
        for (int ks = 0; ks < 4; ks++) {
          bf16x8 bo = *(const bf16x8*)&Kb[trow][swz(trow, kb * 8 + ks * 32)];
          accp[0][nt] = MFMA16(wa[ks], bo, accp[0][nt]);
          accp[1][nt] = MFMA16(wb2[ks], bo, accp[1][nt]);
        }
      }
    }
  }

  // ---- accb write: token = nt*16+lr, outc = wid*32 + mi2*16 + kb*4 + r ----
#pragma unroll
  for (int mi2 = 0; mi2 < 2; mi2++) {
    const int outc = wid * 32 + mi2 * 16 + kb * 4;
    const float b0 = wob[outc], b1 = wob[outc + 1];
    const float b2 = wob[outc + 2], b3 = wob[outc + 3];
#pragma unroll
    for (int nt = 0; nt < 8; nt++) {
      const int token = tok0 + (nt * 16 + lr) * tstep;
      bf16x4 pv = {f2bf(accp[mi2][nt][0] + b0), f2bf(accp[mi2][nt][1] + b1),
                   f2bf(accp[mi2][nt][2] + b2), f2bf(accp[mi2][nt][3] + b3)};
      *(bf16x4*)(accb + (size_t)token * 256 + outc) = pv;
    }
  }
}

// ---- conv1x1: [relu(a0+a1)|xu|res] @ convT^T -> relu -> ytmp(f32) + BN partials
__global__ __launch_bounds__(256) void k_gemm_conv(const short* __restrict__ accb0,
                                                   const short* __restrict__ accb1,
                                                   const short* __restrict__ xu,
                                                   const float* __restrict__ res,
                                                   const short* __restrict__ Bt,
                                                   float* __restrict__ ytmp,
                                                   float* __restrict__ partial) {
  __shared__ float redS[2][128], redS2[2][128];
  const int tid = threadIdx.x;
  const int lane = tid & 63, wid = tid >> 6;
  const int lr = lane & 15, kb = lane >> 4;
  const int wr = wid >> 1, wc = wid & 1;
  const int m0 = blockIdx.y * 128;
  f32x4 acc[4][4];
#pragma unroll
  for (int i = 0; i < 4; i++)
#pragma unroll
    for (int j = 0; j < 4; j++) acc[i][j] = (f32x4){0.f, 0.f, 0.f, 0.f};
  const short* arow0 = accb0 + (size_t)(m0 + wr * 64 + lr) * 256 + kb * 8;
  const short* arow1 = accb1 + (size_t)(m0 + wr * 64 + lr) * 256 + kb * 8;
  const short* arow2 = xu + (size_t)(m0 + wr * 64 + lr) * 256 + kb * 8;
  const short* brow = Bt + (size_t)(wc * 64 + lr) * 640 + kb * 8;
#pragma unroll
  for (int ks = 0; ks < 8; ks++) {
    bf16x8 a[4], b[4];
#pragma unroll
    for (int mi = 0; mi < 4; mi++) {
      bf16x8 t0 = *(const bf16x8*)(arow0 + (size_t)mi * 16 * 256 + ks * 32);
      bf16x8 t1 = *(const bf16x8*)(arow1 + (size_t)mi * 16 * 256 + ks * 32);
      bf16x8 tv;
#pragma unroll
      for (int u = 0; u < 8; u++) {
        float sv = bf2f(t0[u]) + bf2f(t1[u]);
        tv[u] = f2bf(fmaxf(sv, 0.f));
      }
      a[mi] = tv;
    }
#pragma unroll
    for (int nj = 0; nj < 4; nj++)
      b[nj] = *(const bf16x8*)(brow + (size_t)nj * 16 * 640 + ks * 32);
#pragma unroll
    for (int mi = 0; mi < 4; mi++)
#pragma unroll
      for (int nj = 0; nj < 4; nj++)
        acc[mi][nj] = MFMA16(a[mi], b[nj], acc[mi][nj]);
  }
#pragma unroll
  for (int ks = 8; ks < 16; ks++) {
    bf16x8 a[4], b[4];
#pragma unroll
    for (int mi = 0; mi < 4; mi++)
      a[mi] = *(const bf16x8*)(arow2 + (size_t)mi * 16 * 256 + (ks - 8) * 32);
#pragma unroll
    for (int nj = 0; nj < 4; nj++)
      b[nj] = *(const bf16x8*)(brow + (size_t)nj * 16 * 640 + ks * 32);
#pragma unroll
    for (int mi = 0; mi < 4; mi++)
#pragma unroll
      for (int nj = 0; nj < 4; nj++)
        acc[mi][nj] = MFMA16(a[mi], b[nj], acc[mi][nj]);
  }
  const int bC = (m0 >> 14) * 128;
  const int hh = (m0 >> 7) & 127;
#pragma unroll
  for (int ks = 16; ks < 20; ks++) {
    const int e0 = (ks - 16) * 32 + kb * 8;
    bf16x8 a[4], b[4];
#pragma unroll
    for (int mi = 0; mi < 4; mi++) {
      const int wl = wr * 64 + mi * 16 + lr;
      const float* rp = res + ((size_t)(bC + e0) * 128 + hh) * 128 + wl;
      bf16x8 tv;
#pragma unroll
      for (int u = 0; u < 8; u++) tv[u] = f2bf(rp[(size_t)u * 16384]);
      a[mi] = tv;
    }
#pragma unroll
    for (int nj = 0; nj < 4; nj++)
      b[nj] = *(const bf16x8*)(brow + (size_t)nj * 16 * 640 + ks * 32);
#pragma unroll
    for (int mi = 0; mi < 4; mi++)
#pragma unroll
      for (int nj = 0; nj < 4; nj++)
        acc[mi][nj] = MFMA16(a[mi], b[nj], acc[mi][nj]);
  }
  // epilogue: relu -> f32 ytmp + per-channel partial sums (exact f32)
#pragma unroll
  for (int nj = 0; nj < 4; nj++) {
    float s = 0.f, s2 = 0.f;
    const int c = wc * 64 + nj * 16 + lr;
#pragma unroll
    for (int mi = 0; mi < 4; mi++) {
      const int rbase = m0 + wr * 64 + mi * 16 + kb * 4;
#pragma unroll
      for (int r = 0; r < 4; r++) {
        const float yv = fmaxf(acc[mi][nj][r], 0.f);
        ytmp[(size_t)(rbase + r) * 128 + c] = yv;
        s += yv; s2 += yv * yv;
      }
    }
    s += __shfl_xor(s, 16);  s += __shfl_xor(s, 32);
    s2 += __shfl_xor(s2, 16); s2 += __shfl_xor(s2, 32);
    if (kb == 0) { redS[wr][c] = s; redS2[wr][c] = s2; }
  }
  __syncthreads();
  if (tid < 128) {
    partial[((size_t)blockIdx.y * 128 + tid) * 2]     = redS[0][tid] + redS[1][tid];
    partial[((size_t)blockIdx.y * 128 + tid) * 2 + 1] = redS2[0][tid] + redS2[1][tid];
  }
}

// ---------------- BN stats final reduce ----------------
__global__ __launch_bounds__(128) void k_bnstats2(const float* __restrict__ partial,
                                                  float* __restrict__ stats) {
  const int ch = threadIdx.x;
  float s = 0.f, s2 = 0.f;
  for (int i = 0; i < 512; i++) {
    s  += partial[(size_t)(i * 128 + ch) * 2];
    s2 += partial[(size_t)(i * 128 + ch) * 2 + 1];
  }
  const float mu = s * (1.f / 65536.f);
  const float var = s2 * (1.f / 65536.f) - mu * mu;
  stats[ch * 2] = mu;
  stats[ch * 2 + 1] = rsqrtf(var + 1e-5f);
}

// ---------------- BN apply + transpose to (B,E,H,W), coalesced writes -------
__global__ __launch_bounds__(256) void k_bnout(const float* __restrict__ y,
                                               const float* __restrict__ stats,
                                               const float* __restrict__ gamma,
                                               const float* __restrict__ beta,
                                               float* __restrict__ out) {
  const int bh = blockIdx.x;
  const int b = bh >> 7, h = bh & 127;
  const int w = threadIdx.x & 127, half = threadIdx.x >> 7;
  const float* yp = y + (size_t)(bh * 128 + w) * 128 + half * 64;
  float* op = out + ((size_t)(b * 128) << 14) + h * 128 + w;
#pragma unroll
  for (int e4 = 0; e4 < 16; e4++) {
    f32x4 v = *(const f32x4*)(yp + e4 * 4);
#pragma unroll
    for (int u = 0; u < 4; u++) {
      const int e = half * 64 + e4 * 4 + u;
      const float mu = stats[e * 2], rstd = stats[e * 2 + 1];
      op[(size_t)e << 14] = (v[u] - mu) * rstd * gamma[e] + beta[e];
    }
  }
}

// ---------------- launcher ----------------
extern "C" void kernel_launch(void* const* d_in, const int* in_sizes, int n_in,
                              void* d_out, int out_size, void* d_ws, size_t ws_size,
                              hipStream_t stream) {
  const float* x      = (const float*)d_in[0];
  const float* res    = (const float*)d_in[1];
  const float* wq_h   = (const float*)d_in[2];
  const float* wkv_h  = (const float*)d_in[3];
  const float* wo_h   = (const float*)d_in[4];
  const float* wob_h  = (const float*)d_in[5];
  const float* wq_w   = (const float*)d_in[6];
  const float* wkv_w  = (const float*)d_in[7];
  const float* wo_w   = (const float*)d_in[8];
  const float* wob_w  = (const float*)d_in[9];
  const float* conv_w = (const float*)d_in[10];
  const float* gamma  = (const float*)d_in[11];
  const float* beta   = (const float*)d_in[12];

  char* ws = (char*)d_ws;
  short* wqkvT[2] = {(short*)(ws + 0), (short*)(ws + 393216)};
  short* woT[2]   = {(short*)(ws + 786432), (short*)(ws + 917504)};
  short* convT    = (short*)(ws + 1048576);
  short* xu       = (short*)(ws + 1245184);
  float* ytmp     = (float*)(ws + 34799616);
  float* partial  = (float*)(ws + 68354048);
  float* stats    = (float*)(ws + 68878336);
  short* accb1    = (short*)(ws + 68879360);
  short* xuT      = (short*)(ws + 102433792);
  short* accb0    = (short*)d_out;             // dir-0 axial output in d_out
  float* out      = (float*)d_out;

  if (ws_size < 135988224ull)
    fprintf(stderr, "kernel_launch: ws_size %zu too small\n", ws_size);

  // fused weight prep: starts 0,64,192,256,384,448,512; total 592 tiles
  WtAll P;
  P.src[0] = wq_h;  P.dst[0] = wqkvT[0];          P.K[0] = 256; P.N[0] = 256; P.tile0[0] = 0;
  P.src[1] = wkv_h; P.dst[1] = wqkvT[0] + 65536;  P.K[1] = 256; P.N[1] = 512; P.tile0[1] = 64;
  P.src[2] = wq_w;  P.dst[2] = wqkvT[1];          P.K[2] = 256; P.N[2] = 256; P.tile0[2] = 192;
  P.src[3] = wkv_w; P.dst[3] = wqkvT[1] + 65536;  P.K[3] = 256; P.N[3] = 512; P.tile0[3] = 256;
  P.src[4] = wo_h;  P.dst[4] = woT[0];            P.K[4] = 256; P.N[4] = 256; P.tile0[4] = 384;
  P.src[5] = wo_w;  P.dst[5] = woT[1];            P.K[5] = 256; P.N[5] = 256; P.tile0[5] = 448;
  P.src[6] = conv_w;P.dst[6] = convT;             P.K[6] = 640; P.N[6] = 128; P.tile0[6] = 512;
  k_wt_all<<<592, 256, 0, stream>>>(P);

  k_upsample<<<dim3(512, 4), 256, 0, stream>>>(x, xu, xuT);

  k_fused<<<dim3(512, 2), 512, 0, stream>>>(xu, xuT, wqkvT[0], woT[0],
                                            wob_h, wob_w, accb0, accb1);

  k_gemm_conv<<<dim3(1, 512), 256, 0, stream>>>(accb0, accb1, xu, res, convT,
                                                ytmp, partial);
  k_bnstats2<<<1, 128, 0, stream>>>(partial, stats);
  k_bnout<<<512, 256, 0, stream>>>(ytmp, stats, gamma, beta, out);
}

// Round 13
// 247.772 us; speedup vs baseline: 3.8130x; 2.2136x over previous
//
#include <hip/hip_runtime.h>
#include <hip/hip_bf16.h>
#include <cstdio>

// BlockAxialUp on MI355X, round 13: consolidation = round-10 kernel verbatim
// (session best, 248us). Rounds 11/12 both regressed with the same spill /
// re-read signature; the Xs LDS stage + (512,2) launch bounds are load-bearing:
//  - Xs stage => each block reads its 64KB X slab from HBM exactly once
//  - (512,2)  => 256-VGPR budget; (.,4) caps at 64-128 and spills GBs
//
// ws layout (bytes):
//   0         wqkvT_h bf16 [768][256] (q 0:256, k 256:512, v 512:768)
//   393216    wqkvT_w
//   786432    woT_h  bf16 [256][256]
//   917504    woT_w
//   1048576   convT  bf16 [128][640]
//   1245184   xu     bf16 [65536][256]
//   34799616  ytmp   f32  [65536][128]
//   68354048  partial f32 [512][128][2]
//   68878336  stats  f32  [128][2]
//   68879360  accb1  bf16 [65536][256]  -> end 102433792
// accb0 (dir-0) lives in d_out; final f32 output overwrites it.

typedef short bf16x8 __attribute__((ext_vector_type(8)));
typedef short bf16x4 __attribute__((ext_vector_type(4)));
typedef float f32x4 __attribute__((ext_vector_type(4)));

#define MFMA16(a, b, c) __builtin_amdgcn_mfma_f32_16x16x32_bf16((a), (b), (c), 0, 0, 0)

__device__ __forceinline__ short f2bf(float v) {
  __hip_bfloat16 h = __float2bfloat16(v);
  union { __hip_bfloat16 h; short s; } u; u.h = h; return u.s;
}
__device__ __forceinline__ float bf2f(short s) {
  return __uint_as_float(((unsigned int)(unsigned short)s) << 16);
}
// XOR swizzle, granule = 8 shorts (16 B); flips col bits 3-5 only.
__device__ __forceinline__ int swz(int row, int col) {
  return col ^ ((row & 7) << 3);
}

// ---------------- fused weight prep: dst[n][k] = bf16(src[k][n]) ------------
struct WtAll {
  const float* src[7];
  short* dst[7];
  int K[7], N[7], tile0[7];
};

__global__ __launch_bounds__(256) void k_wt_all(WtAll P) {
  const int bid = blockIdx.x;
  int i = 0;
#pragma unroll
  for (int j = 1; j < 7; j++) if (bid >= P.tile0[j]) i = j;
  const float* src = P.src[i];
  short* dst = P.dst[i];
  const int K = P.K[i], N = P.N[i];
  const int local = bid - P.tile0[i];
  const int ktiles = K >> 5;
  const int nt = local / ktiles, kt = local - nt * ktiles;
  const int k0 = kt * 32, n0 = nt * 32;
  __shared__ float tile[32][33];
  const int tx = threadIdx.x & 31, ty = threadIdx.x >> 5;
#pragma unroll
  for (int r = 0; r < 4; r++)
    tile[ty + r * 8][tx] = src[(size_t)(k0 + ty + r * 8) * N + n0 + tx];
  __syncthreads();
#pragma unroll
  for (int r = 0; r < 4; r++)
    dst[(size_t)(n0 + ty + r * 8) * K + k0 + tx] = f2bf(tile[tx][ty + r * 8]);
}

// ---------------- upsample 2x bilinear align_corners --------------------
__global__ __launch_bounds__(256) void k_upsample(const float* __restrict__ x,
                                                  short* __restrict__ xu) {
  __shared__ float ldsV[64][65];
  const int bh = blockIdx.x, z = blockIdx.y;
  const int b = bh >> 7, h = bh & 127;
  const float chf = h * (63.0f / 127.0f);
  int i0 = (int)chf; if (i0 > 62) i0 = 62;
  const float wh = chf - (float)i0;
  const int t = threadIdx.x;
  const int cbase = z * 64;
  const float* xb = x + ((size_t)(b * 256 + cbase) * 64 + i0) * 64;
#pragma unroll
  for (int p = 0; p < 16; p++) {
    const int li = p * 256 + t;
    const int c = li >> 6, w = li & 63;
    const float* px = xb + (size_t)c * 4096 + w;
    const float v0 = px[0], v1 = px[64];
    ldsV[c][w] = v0 * (1.f - wh) + v1 * wh;
  }
  __syncthreads();
  const int cg = t & 7, wi = t >> 3;
  short* xout = xu + (size_t)(bh * 128) * 256 + cbase + cg * 8;
#pragma unroll
  for (int p = 0; p < 4; p++) {
    const int w = p * 32 + wi;
    const float cwf = w * (63.0f / 127.0f);
    int j0 = (int)cwf; if (j0 > 62) j0 = 62;
    const float ww = cwf - (float)j0;
    bf16x8 o;
#pragma unroll
    for (int u = 0; u < 8; u++) {
      const float v0 = ldsV[cg * 8 + u][j0], v1 = ldsV[cg * 8 + u][j0 + 1];
      o[u] = f2bf(v0 * (1.f - ww) + v1 * ww);
    }
    *(bf16x8*)(xout + (size_t)w * 256) = o;
  }
}

// ---------------- fused QKV + attention + proj (round-6 body) ---------------
// grid (512, 2): blockIdx.x = sequence, blockIdx.y = dir. 512 thr = 8 waves.
// LDS: Xs 64K + Qb(P) 32K + Kb(O) 32K + Vtb 32K = 160 KB.
__global__ __launch_bounds__(512, 2) void k_fused(const short* __restrict__ xu,
                                                  const short* __restrict__ wqkvT0,
                                                  const short* __restrict__ woT0,
                                                  const float* __restrict__ wob0,
                                                  const float* __restrict__ wob1,
                                                  short* __restrict__ accb0,
                                                  short* __restrict__ accb1) {
  __shared__ __align__(16) short Xs[128][256];
  __shared__ __align__(16) short Qb[128][128];   // Q, then P
  __shared__ __align__(16) short Kb[128][128];   // K, then O
  __shared__ __align__(16) short Vtb[128][128];  // V^T

  const int dir = blockIdx.y;
  const short* wqkvT = wqkvT0 + (size_t)dir * 196608;
  const short* woT   = woT0 + (size_t)dir * 65536;
  const float* wob   = dir ? wob1 : wob0;
  short* accb        = dir ? accb1 : accb0;

  const int s = blockIdx.x;
  const int b = s >> 7, pos = s & 127;
  const int tok0 = b * 16384 + (dir ? pos * 128 : pos);
  const int tstep = dir ? 1 : 128;
  const int tid = threadIdx.x;
  const int lane = tid & 63, wid = tid >> 6;
  const int lr = lane & 15, kb = lane >> 4;
  const int ct = wid * 16;                    // wave's chan/token tile base
  const float scale = 0.08838834764831845f;  // 128^-0.5

  // ---- stage Xs: 32 lanes cover one 512 B token row ----
#pragma unroll
  for (int p = 0; p < 8; p++) {
    const int u = p * 512 + tid;
    const int row = u >> 5, ck = (u & 31) * 8;
    bf16x8 v = *(const bf16x8*)(xu + (size_t)(tok0 + row * tstep) * 256 + ck);
    *(bf16x8*)&Xs[row][swz(row, ck)] = v;
  }

  f32x4 accp[2][8];
#pragma unroll
  for (int i = 0; i < 2; i++)
#pragma unroll
    for (int j = 0; j < 8; j++) accp[i][j] = (f32x4){0.f, 0.f, 0.f, 0.f};

  for (int h = 0; h < 2; h++) {
    // weight fragments for this head (L1/L2-hot, identical across blocks)
    const short* wqb = wqkvT + (size_t)(h * 128 + ct + lr) * 256 + kb * 8;
    const short* wkb = wqkvT + (size_t)(256 + h * 128 + ct + lr) * 256 + kb * 8;
    const short* wvb = wqkvT + (size_t)(512 + h * 128 + ct + lr) * 256 + kb * 8;
    bf16x8 wq[8], wk[8], wv[8];
#pragma unroll
    for (int ks = 0; ks < 8; ks++) {
      wq[ks] = *(const bf16x8*)(wqb + ks * 32);
      wk[ks] = *(const bf16x8*)(wkb + ks * 32);
      wv[ks] = *(const bf16x8*)(wvb + ks * 32);
    }

    __syncthreads();  // A: Xs staged (h=0) / prev head's proj reads done

    // ---- merged Q/K/V production: one pass over Xs ----
#pragma unroll
    for (int nt = 0; nt < 8; nt++) {
      const int xrow = nt * 16 + lr;
      f32x4 dq = (f32x4){0.f, 0.f, 0.f, 0.f};
      f32x4 dk = (f32x4){0.f, 0.f, 0.f, 0.f};
      f32x4 dv = (f32x4){0.f, 0.f, 0.f, 0.f};
#pragma unroll
      for (int ks = 0; ks < 8; ks++) {
        bf16x8 xf = *(const bf16x8*)&Xs[xrow][swz(xrow, kb * 8 + ks * 32)];
        dq = MFMA16(wq[ks], xf, dq);   // D[chan][token]
        dk = MFMA16(wk[ks], xf, dk);   // D[chan][token]
        dv = MFMA16(xf, wv[ks], dv);   // swapped: D[token][chan]
      }
      const int trow = nt * 16 + lr, cc = ct + kb * 4;
      bf16x4 pq = {f2bf(dq[0]), f2bf(dq[1]), f2bf(dq[2]), f2bf(dq[3])};
      bf16x4 pk = {f2bf(dk[0]), f2bf(dk[1]), f2bf(dk[2]), f2bf(dk[3])};
      *(bf16x4*)&Qb[trow][swz(trow, cc)] = pq;
      *(bf16x4*)&Kb[trow][swz(trow, cc)] = pk;
      const int vrow = ct + lr;
      bf16x4 pv = {f2bf(dv[0]), f2bf(dv[1]), f2bf(dv[2]), f2bf(dv[3])};
      *(bf16x4*)&Vtb[vrow][swz(vrow, nt * 16 + kb * 4)] = pv;
    }

    __syncthreads();  // B: Q/K/Vt visible to all waves

    // ---- S^T = K Q^T : lane owns q-token ct+lr ----
    f32x4 s8[8];
#pragma unroll
    for (int i = 0; i < 8; i++) s8[i] = (f32x4){0.f, 0.f, 0.f, 0.f};
    const int qrow = ct + lr;
#pragma unroll
    for (int ks = 0; ks < 4; ks++) {
      bf16x8 aq = *(const bf16x8*)&Qb[qrow][swz(qrow, kb * 8 + ks * 32)];
#pragma unroll
      for (int nj = 0; nj < 8; nj++) {
        const int krow = nj * 16 + lr;
        bf16x8 bk = *(const bf16x8*)&Kb[krow][swz(krow, kb * 8 + ks * 32)];
        s8[nj] = MFMA16(bk, aq, s8[nj]);   // D[k-token][q-token]
      }
    }
    // ---- per-lane softmax (xor 16, 32); P overwrites own Qb row ----
    {
      float m = s8[0][0];
#pragma unroll
      for (int nj = 0; nj < 8; nj++)
#pragma unroll
        for (int r = 0; r < 4; r++) m = fmaxf(m, s8[nj][r]);
      m = fmaxf(m, __shfl_xor(m, 16));
      m = fmaxf(m, __shfl_xor(m, 32));
      float sum = 0.f;
#pragma unroll
      for (int nj = 0; nj < 8; nj++)
#pragma unroll
        for (int r = 0; r < 4; r++) {
          s8[nj][r] = __expf((s8[nj][r] - m) * scale);
          sum += s8[nj][r];
        }
      sum += __shfl_xor(sum, 16);
      sum += __shfl_xor(sum, 32);
      const float inv = 1.f / sum;
#pragma unroll
      for (int nj = 0; nj < 8; nj++) {
        bf16x4 pp = {f2bf(s8[nj][0] * inv), f2bf(s8[nj][1] * inv),
                     f2bf(s8[nj][2] * inv), f2bf(s8[nj][3] * inv)};
        *(bf16x4*)&Qb[qrow][swz(qrow, nj * 16 + kb * 4)] = pp;
      }
    }

    // ---- O = P V : lane reads own P row (in-wave dep), all Vtb rows ----
    f32x4 o8[8];
#pragma unroll
    for (int i = 0; i < 8; i++) o8[i] = (f32x4){0.f, 0.f, 0.f, 0.f};
#pragma unroll
    for (int ks = 0; ks < 4; ks++) {
      bf16x8 bp = *(const bf16x8*)&Qb[qrow][swz(qrow, kb * 8 + ks * 32)];
#pragma unroll
      for (int mi = 0; mi < 8; mi++) {
        const int vrow = mi * 16 + lr;
        bf16x8 av = *(const bf16x8*)&Vtb[vrow][swz(vrow, kb * 8 + ks * 32)];
        o8[mi] = MFMA16(av, bp, o8[mi]);   // D[chan][q-token]
      }
    }

    __syncthreads();  // C: all waves' S reads of Kb done; O may overwrite

#pragma unroll
    for (int mi = 0; mi < 8; mi++) {
      const int cc = mi * 16 + kb * 4;
      bf16x4 po = {f2bf(o8[mi][0]), f2bf(o8[mi][1]), f2bf(o8[mi][2]), f2bf(o8[mi][3])};
      *(bf16x4*)&Kb[qrow][swz(qrow, cc)] = po;
    }

    __syncthreads();  // D: O complete for all waves

    // ---- proj: out-chans [wid*32, wid*32+32), all tokens ----
    {
      const short* w0 = woT + (size_t)(wid * 32 + lr) * 256 + h * 128 + kb * 8;
      const short* w1 = woT + (size_t)(wid * 32 + 16 + lr) * 256 + h * 128 + kb * 8;
      bf16x8 wa[4], wb2[4];
#pragma unroll
      for (int ks = 0; ks < 4; ks++) {
        wa[ks]  = *(const bf16x8*)(w0 + ks * 32);
        wb2[ks] = *(const bf16x8*)(w1 + ks * 32);
      }
#pragma unroll
      for (int nt = 0; nt < 8; nt++) {
        const int trow = nt * 16 + lr;
#pragma unroll
        for (int ks = 0; ks < 4; ks++) {
          bf16x8 bo = *(const bf16x8*)&Kb[trow][swz(trow, kb * 8 + ks * 32)];
          accp[0][nt] = MFMA16(wa[ks], bo, accp[0][nt]);
          accp[1][nt] = MFMA16(wb2[ks], bo, accp[1][nt]);
        }
      }
    }
  }

  // ---- accb write: token = nt*16+lr, outc = wid*32 + mi2*16 + kb*4 + r ----
#pragma unroll
  for (int mi2 = 0; mi2 < 2; mi2++) {
    const int outc = wid * 32 + mi2 * 16 + kb * 4;
    const float b0 = wob[outc], b1 = wob[outc + 1];
    const float b2 = wob[outc + 2], b3 = wob[outc + 3];
#pragma unroll
    for (int nt = 0; nt < 8; nt++) {
      const int token = tok0 + (nt * 16 + lr) * tstep;
      bf16x4 pv = {f2bf(accp[mi2][nt][0] + b0), f2bf(accp[mi2][nt][1] + b1),
                   f2bf(accp[mi2][nt][2] + b2), f2bf(accp[mi2][nt][3] + b3)};
      *(bf16x4*)(accb + (size_t)token * 256 + outc) = pv;
    }
  }
}

// ---- conv1x1: [relu(a0+a1)|xu|res] @ convT^T -> relu -> ytmp(f32) + BN partials
__global__ __launch_bounds__(256) void k_gemm_conv(const short* __restrict__ accb0,
                                                   const short* __restrict__ accb1,
                                                   const short* __restrict__ xu,
                                                   const float* __restrict__ res,
                                                   const short* __restrict__ Bt,
                                                   float* __restrict__ ytmp,
                                                   float* __restrict__ partial) {
  __shared__ float redS[2][128], redS2[2][128];
  const int tid = threadIdx.x;
  const int lane = tid & 63, wid = tid >> 6;
  const int lr = lane & 15, kb = lane >> 4;
  const int wr = wid >> 1, wc = wid & 1;
  const int m0 = blockIdx.y * 128;
  f32x4 acc[4][4];
#pragma unroll
  for (int i = 0; i < 4; i++)
#pragma unroll
    for (int j = 0; j < 4; j++) acc[i][j] = (f32x4){0.f, 0.f, 0.f, 0.f};
  const short* arow0 = accb0 + (size_t)(m0 + wr * 64 + lr) * 256 + kb * 8;
  const short* arow1 = accb1 + (size_t)(m0 + wr * 64 + lr) * 256 + kb * 8;
  const short* arow2 = xu + (size_t)(m0 + wr * 64 + lr) * 256 + kb * 8;
  const short* brow = Bt + (size_t)(wc * 64 + lr) * 640 + kb * 8;
#pragma unroll
  for (int ks = 0; ks < 8; ks++) {
    bf16x8 a[4], b[4];
#pragma unroll
    for (int mi = 0; mi < 4; mi++) {
      bf16x8 t0 = *(const bf16x8*)(arow0 + (size_t)mi * 16 * 256 + ks * 32);
      bf16x8 t1 = *(const bf16x8*)(arow1 + (size_t)mi * 16 * 256 + ks * 32);
      bf16x8 tv;
#pragma unroll
      for (int u = 0; u < 8; u++) {
        float sv = bf2f(t0[u]) + bf2f(t1[u]);
        tv[u] = f2bf(fmaxf(sv, 0.f));
      }
      a[mi] = tv;
    }
#pragma unroll
    for (int nj = 0; nj < 4; nj++)
      b[nj] = *(const bf16x8*)(brow + (size_t)nj * 16 * 640 + ks * 32);
#pragma unroll
    for (int mi = 0; mi < 4; mi++)
#pragma unroll
      for (int nj = 0; nj < 4; nj++)
        acc[mi][nj] = MFMA16(a[mi], b[nj], acc[mi][nj]);
  }
#pragma unroll
  for (int ks = 8; ks < 16; ks++) {
    bf16x8 a[4], b[4];
#pragma unroll
    for (int mi = 0; mi < 4; mi++)
      a[mi] = *(const bf16x8*)(arow2 + (size_t)mi * 16 * 256 + (ks - 8) * 32);
#pragma unroll
    for (int nj = 0; nj < 4; nj++)
      b[nj] = *(const bf16x8*)(brow + (size_t)nj * 16 * 640 + ks * 32);
#pragma unroll
    for (int mi = 0; mi < 4; mi++)
#pragma unroll
      for (int nj = 0; nj < 4; nj++)
        acc[mi][nj] = MFMA16(a[mi], b[nj], acc[mi][nj]);
  }
  const int bC = (m0 >> 14) * 128;
  const int hh = (m0 >> 7) & 127;
#pragma unroll
  for (int ks = 16; ks < 20; ks++) {
    const int e0 = (ks - 16) * 32 + kb * 8;
    bf16x8 a[4], b[4];
#pragma unroll
    for (int mi = 0; mi < 4; mi++) {
      const int wl = wr * 64 + mi * 16 + lr;
      const float* rp = res + ((size_t)(bC + e0) * 128 + hh) * 128 + wl;
      bf16x8 tv;
#pragma unroll
      for (int u = 0; u < 8; u++) tv[u] = f2bf(rp[(size_t)u * 16384]);
      a[mi] = tv;
    }
#pragma unroll
    for (int nj = 0; nj < 4; nj++)
      b[nj] = *(const bf16x8*)(brow + (size_t)nj * 16 * 640 + ks * 32);
#pragma unroll
    for (int mi = 0; mi < 4; mi++)
#pragma unroll
      for (int nj = 0; nj < 4; nj++)
        acc[mi][nj] = MFMA16(a[mi], b[nj], acc[mi][nj]);
  }
  // epilogue: relu -> f32 ytmp + per-channel partial sums (exact f32)
#pragma unroll
  for (int nj = 0; nj < 4; nj++) {
    float s = 0.f, s2 = 0.f;
    const int c = wc * 64 + nj * 16 + lr;
#pragma unroll
    for (int mi = 0; mi < 4; mi++) {
      const int rbase = m0 + wr * 64 + mi * 16 + kb * 4;
#pragma unroll
      for (int r = 0; r < 4; r++) {
        const float yv = fmaxf(acc[mi][nj][r], 0.f);
        ytmp[(size_t)(rbase + r) * 128 + c] = yv;
        s += yv; s2 += yv * yv;
      }
    }
    s += __shfl_xor(s, 16);  s += __shfl_xor(s, 32);
    s2 += __shfl_xor(s2, 16); s2 += __shfl_xor(s2, 32);
    if (kb == 0) { redS[wr][c] = s; redS2[wr][c] = s2; }
  }
  __syncthreads();
  if (tid < 128) {
    partial[((size_t)blockIdx.y * 128 + tid) * 2]     = redS[0][tid] + redS[1][tid];
    partial[((size_t)blockIdx.y * 128 + tid) * 2 + 1] = redS2[0][tid] + redS2[1][tid];
  }
}

// ---------------- BN stats final reduce ----------------
__global__ __launch_bounds__(128) void k_bnstats2(const float* __restrict__ partial,
                                                  float* __restrict__ stats) {
  const int ch = threadIdx.x;
  float s = 0.f, s2 = 0.f;
  for (int i = 0; i < 512; i++) {
    s  += partial[(size_t)(i * 128 + ch) * 2];
    s2 += partial[(size_t)(i * 128 + ch) * 2 + 1];
  }
  const float mu = s * (1.f / 65536.f);
  const float var = s2 * (1.f / 65536.f) - mu * mu;
  stats[ch * 2] = mu;
  stats[ch * 2 + 1] = rsqrtf(var + 1e-5f);
}

// ---------------- BN apply + transpose to (B,E,H,W), coalesced writes -------
__global__ __launch_bounds__(256) void k_bnout(const float* __restrict__ y,
                                               const float* __restrict__ stats,
                                               const float* __restrict__ gamma,
                                               const float* __restrict__ beta,
                                               float* __restrict__ out) {
  const int bh = blockIdx.x;
  const int b = bh >> 7, h = bh & 127;
  const int w = threadIdx.x & 127, half = threadIdx.x >> 7;
  const float* yp = y + (size_t)(bh * 128 + w) * 128 + half * 64;
  float* op = out + ((size_t)(b * 128) << 14) + h * 128 + w;
#pragma unroll
  for (int e4 = 0; e4 < 16; e4++) {
    f32x4 v = *(const f32x4*)(yp + e4 * 4);
#pragma unroll
    for (int u = 0; u < 4; u++) {
      const int e = half * 64 + e4 * 4 + u;
      const float mu = stats[e * 2], rstd = stats[e * 2 + 1];
      op[(size_t)e << 14] = (v[u] - mu) * rstd * gamma[e] + beta[e];
    }
  }
}

// ---------------- launcher ----------------
extern "C" void kernel_launch(void* const* d_in, const int* in_sizes, int n_in,
                              void* d_out, int out_size, void* d_ws, size_t ws_size,
                              hipStream_t stream) {
  const float* x      = (const float*)d_in[0];
  const float* res    = (const float*)d_in[1];
  const float* wq_h   = (const float*)d_in[2];
  const float* wkv_h  = (const float*)d_in[3];
  const float* wo_h   = (const float*)d_in[4];
  const float* wob_h  = (const float*)d_in[5];
  const float* wq_w   = (const float*)d_in[6];
  const float* wkv_w  = (const float*)d_in[7];
  const float* wo_w   = (const float*)d_in[8];
  const float* wob_w  = (const float*)d_in[9];
  const float* conv_w = (const float*)d_in[10];
  const float* gamma  = (const float*)d_in[11];
  const float* beta   = (const float*)d_in[12];

  char* ws = (char*)d_ws;
  short* wqkvT[2] = {(short*)(ws + 0), (short*)(ws + 393216)};
  short* woT[2]   = {(short*)(ws + 786432), (short*)(ws + 917504)};
  short* convT    = (short*)(ws + 1048576);
  short* xu       = (short*)(ws + 1245184);
  float* ytmp     = (float*)(ws + 34799616);
  float* partial  = (float*)(ws + 68354048);
  float* stats    = (float*)(ws + 68878336);
  short* accb1    = (short*)(ws + 68879360);
  short* accb0    = (short*)d_out;             // dir-0 axial output in d_out
  float* out      = (float*)d_out;

  if (ws_size < 102433792ull)
    fprintf(stderr, "kernel_launch: ws_size %zu too small\n", ws_size);

  // fused weight prep: starts 0,64,192,256,384,448,512; total 592 tiles
  WtAll P;
  P.src[0] = wq_h;  P.dst[0] = wqkvT[0];          P.K[0] = 256; P.N[0] = 256; P.tile0[0] = 0;
  P.src[1] = wkv_h; P.dst[1] = wqkvT[0] + 65536;  P.K[1] = 256; P.N[1] = 512; P.tile0[1] = 64;
  P.src[2] = wq_w;  P.dst[2] = wqkvT[1];          P.K[2] = 256; P.N[2] = 256; P.tile0[2] = 192;
  P.src[3] = wkv_w; P.dst[3] = wqkvT[1] + 65536;  P.K[3] = 256; P.N[3] = 512; P.tile0[3] = 256;
  P.src[4] = wo_h;  P.dst[4] = woT[0];            P.K[4] = 256; P.N[4] = 256; P.tile0[4] = 384;
  P.src[5] = wo_w;  P.dst[5] = woT[1];            P.K[5] = 256; P.N[5] = 256; P.tile0[5] = 448;
  P.src[6] = conv_w;P.dst[6] = convT;             P.K[6] = 640; P.N[6] = 128; P.tile0[6] = 512;
  k_wt_all<<<592, 256, 0, stream>>>(P);

  k_upsample<<<dim3(512, 4), 256, 0, stream>>>(x, xu);

  k_fused<<<dim3(512, 2), 512, 0, stream>>>(xu, wqkvT[0], woT[0],
                                            wob_h, wob_w, accb0, accb1);

  k_gemm_conv<<<dim3(1, 512), 256, 0, stream>>>(accb0, accb1, xu, res, convT,
                                                ytmp, partial);
  k_bnstats2<<<1, 128, 0, stream>>>(partial, stats);
  k_bnout<<<512, 256, 0, stream>>>(ytmp, stats, gamma, beta, out);
}

// Round 14
// 229.126 us; speedup vs baseline: 4.1233x; 1.0814x over previous
//
#include <hip/hip_runtime.h>
#include <hip/hip_bf16.h>
#include <cstdio>

// BlockAxialUp on MI355X, round 14: round-13 base + three proven low-risk cuts.
//  - k_fused: O overwrites the lane's OWN P row in Qb (was Kb) -> barrier C
//    removed (8 -> 6 barriers/block). Same within-wave LDS ordering the kernel
//    has used since r6 for P-over-Q.
//  - ytmp bf16 (r8-proven, absmax 0.0625 < 0.171): -32MB tail traffic.
//  - bnstats2: 128 blocks x 1 wave (was 1 block serial).
//  - bnout: r8's coalesced bf16-input version.
//
// ws layout (bytes):
//   0         wqkvT_h bf16 [768][256] (q 0:256, k 256:512, v 512:768)
//   393216    wqkvT_w
//   786432    woT_h  bf16 [256][256]
//   917504    woT_w
//   1048576   convT  bf16 [128][640]
//   1245184   xu     bf16 [65536][256]
//   34799616  ytmp   bf16 [65536][128]
//   51576832  partial f32 [512][128][2]
//   52101120  stats  f32  [128][2]
//   52102144  accb1  bf16 [65536][256]  -> end 85656576
// accb0 (dir-0) lives in d_out; final f32 output overwrites it.

typedef short bf16x8 __attribute__((ext_vector_type(8)));
typedef short bf16x4 __attribute__((ext_vector_type(4)));
typedef float f32x4 __attribute__((ext_vector_type(4)));

#define MFMA16(a, b, c) __builtin_amdgcn_mfma_f32_16x16x32_bf16((a), (b), (c), 0, 0, 0)

__device__ __forceinline__ short f2bf(float v) {
  __hip_bfloat16 h = __float2bfloat16(v);
  union { __hip_bfloat16 h; short s; } u; u.h = h; return u.s;
}
__device__ __forceinline__ float bf2f(short s) {
  return __uint_as_float(((unsigned int)(unsigned short)s) << 16);
}
// XOR swizzle, granule = 8 shorts (16 B); flips col bits 3-5 only.
__device__ __forceinline__ int swz(int row, int col) {
  return col ^ ((row & 7) << 3);
}

// ---------------- fused weight prep: dst[n][k] = bf16(src[k][n]) ------------
struct WtAll {
  const float* src[7];
  short* dst[7];
  int K[7], N[7], tile0[7];
};

__global__ __launch_bounds__(256) void k_wt_all(WtAll P) {
  const int bid = blockIdx.x;
  int i = 0;
#pragma unroll
  for (int j = 1; j < 7; j++) if (bid >= P.tile0[j]) i = j;
  const float* src = P.src[i];
  short* dst = P.dst[i];
  const int K = P.K[i], N = P.N[i];
  const int local = bid - P.tile0[i];
  const int ktiles = K >> 5;
  const int nt = local / ktiles, kt = local - nt * ktiles;
  const int k0 = kt * 32, n0 = nt * 32;
  __shared__ float tile[32][33];
  const int tx = threadIdx.x & 31, ty = threadIdx.x >> 5;
#pragma unroll
  for (int r = 0; r < 4; r++)
    tile[ty + r * 8][tx] = src[(size_t)(k0 + ty + r * 8) * N + n0 + tx];
  __syncthreads();
#pragma unroll
  for (int r = 0; r < 4; r++)
    dst[(size_t)(n0 + ty + r * 8) * K + k0 + tx] = f2bf(tile[tx][ty + r * 8]);
}

// ---------------- upsample 2x bilinear align_corners --------------------
__global__ __launch_bounds__(256) void k_upsample(const float* __restrict__ x,
                                                  short* __restrict__ xu) {
  __shared__ float ldsV[64][65];
  const int bh = blockIdx.x, z = blockIdx.y;
  const int b = bh >> 7, h = bh & 127;
  const float chf = h * (63.0f / 127.0f);
  int i0 = (int)chf; if (i0 > 62) i0 = 62;
  const float wh = chf - (float)i0;
  const int t = threadIdx.x;
  const int cbase = z * 64;
  const float* xb = x + ((size_t)(b * 256 + cbase) * 64 + i0) * 64;
#pragma unroll
  for (int p = 0; p < 16; p++) {
    const int li = p * 256 + t;
    const int c = li >> 6, w = li & 63;
    const float* px = xb + (size_t)c * 4096 + w;
    const float v0 = px[0], v1 = px[64];
    ldsV[c][w] = v0 * (1.f - wh) + v1 * wh;
  }
  __syncthreads();
  const int cg = t & 7, wi = t >> 3;
  short* xout = xu + (size_t)(bh * 128) * 256 + cbase + cg * 8;
#pragma unroll
  for (int p = 0; p < 4; p++) {
    const int w = p * 32 + wi;
    const float cwf = w * (63.0f / 127.0f);
    int j0 = (int)cwf; if (j0 > 62) j0 = 62;
    const float ww = cwf - (float)j0;
    bf16x8 o;
#pragma unroll
    for (int u = 0; u < 8; u++) {
      const float v0 = ldsV[cg * 8 + u][j0], v1 = ldsV[cg * 8 + u][j0 + 1];
      o[u] = f2bf(v0 * (1.f - ww) + v1 * ww);
    }
    *(bf16x8*)(xout + (size_t)w * 256) = o;
  }
}

// ---------------- fused QKV + attention + proj ------------------------------
// grid (512, 2): blockIdx.x = sequence, blockIdx.y = dir. 512 thr = 8 waves.
// LDS: Xs 64K + Qb(Q->P->O) 32K + Kb(K) 32K + Vtb 32K = 160 KB.
__global__ __launch_bounds__(512, 2) void k_fused(const short* __restrict__ xu,
                                                  const short* __restrict__ wqkvT0,
                                                  const short* __restrict__ woT0,
                                                  const float* __restrict__ wob0,
                                                  const float* __restrict__ wob1,
                                                  short* __restrict__ accb0,
                                                  short* __restrict__ accb1) {
  __shared__ __align__(16) short Xs[128][256];
  __shared__ __align__(16) short Qb[128][128];   // Q, then P, then O
  __shared__ __align__(16) short Kb[128][128];   // K
  __shared__ __align__(16) short Vtb[128][128];  // V^T

  const int dir = blockIdx.y;
  const short* wqkvT = wqkvT0 + (size_t)dir * 196608;
  const short* woT   = woT0 + (size_t)dir * 65536;
  const float* wob   = dir ? wob1 : wob0;
  short* accb        = dir ? accb1 : accb0;

  const int s = blockIdx.x;
  const int b = s >> 7, pos = s & 127;
  const int tok0 = b * 16384 + (dir ? pos * 128 : pos);
  const int tstep = dir ? 1 : 128;
  const int tid = threadIdx.x;
  const int lane = tid & 63, wid = tid >> 6;
  const int lr = lane & 15, kb = lane >> 4;
  const int ct = wid * 16;                    // wave's chan/token tile base
  const float scale = 0.08838834764831845f;  // 128^-0.5

  // ---- stage Xs: 32 lanes cover one 512 B token row ----
#pragma unroll
  for (int p = 0; p < 8; p++) {
    const int u = p * 512 + tid;
    const int row = u >> 5, ck = (u & 31) * 8;
    bf16x8 v = *(const bf16x8*)(xu + (size_t)(tok0 + row * tstep) * 256 + ck);
    *(bf16x8*)&Xs[row][swz(row, ck)] = v;
  }

  f32x4 accp[2][8];
#pragma unroll
  for (int i = 0; i < 2; i++)
#pragma unroll
    for (int j = 0; j < 8; j++) accp[i][j] = (f32x4){0.f, 0.f, 0.f, 0.f};

  for (int h = 0; h < 2; h++) {
    // weight fragments for this head (L1/L2-hot, identical across blocks)
    const short* wqb = wqkvT + (size_t)(h * 128 + ct + lr) * 256 + kb * 8;
    const short* wkb = wqkvT + (size_t)(256 + h * 128 + ct + lr) * 256 + kb * 8;
    const short* wvb = wqkvT + (size_t)(512 + h * 128 + ct + lr) * 256 + kb * 8;
    bf16x8 wq[8], wk[8], wv[8];
#pragma unroll
    for (int ks = 0; ks < 8; ks++) {
      wq[ks] = *(const bf16x8*)(wqb + ks * 32);
      wk[ks] = *(const bf16x8*)(wkb + ks * 32);
      wv[ks] = *(const bf16x8*)(wvb + ks * 32);
    }

    __syncthreads();  // A: Xs staged (h=0) / prev head's proj reads of Qb done

    // ---- merged Q/K/V production: one pass over Xs ----
#pragma unroll
    for (int nt = 0; nt < 8; nt++) {
      const int xrow = nt * 16 + lr;
      f32x4 dq = (f32x4){0.f, 0.f, 0.f, 0.f};
      f32x4 dk = (f32x4){0.f, 0.f, 0.f, 0.f};
      f32x4 dv = (f32x4){0.f, 0.f, 0.f, 0.f};
#pragma unroll
      for (int ks = 0; ks < 8; ks++) {
        bf16x8 xf = *(const bf16x8*)&Xs[xrow][swz(xrow, kb * 8 + ks * 32)];
        dq = MFMA16(wq[ks], xf, dq);   // D[chan][token]
        dk = MFMA16(wk[ks], xf, dk);   // D[chan][token]
        dv = MFMA16(xf, wv[ks], dv);   // swapped: D[token][chan]
      }
      const int trow = nt * 16 + lr, cc = ct + kb * 4;
      bf16x4 pq = {f2bf(dq[0]), f2bf(dq[1]), f2bf(dq[2]), f2bf(dq[3])};
      bf16x4 pk = {f2bf(dk[0]), f2bf(dk[1]), f2bf(dk[2]), f2bf(dk[3])};
      *(bf16x4*)&Qb[trow][swz(trow, cc)] = pq;
      *(bf16x4*)&Kb[trow][swz(trow, cc)] = pk;
      const int vrow = ct + lr;
      bf16x4 pv = {f2bf(dv[0]), f2bf(dv[1]), f2bf(dv[2]), f2bf(dv[3])};
      *(bf16x4*)&Vtb[vrow][swz(vrow, nt * 16 + kb * 4)] = pv;
    }

    __syncthreads();  // B: Q/K/Vt visible to all waves

    // ---- S^T = K Q^T : lane owns q-token ct+lr ----
    f32x4 s8[8];
#pragma unroll
    for (int i = 0; i < 8; i++) s8[i] = (f32x4){0.f, 0.f, 0.f, 0.f};
    const int qrow = ct + lr;
#pragma unroll
    for (int ks = 0; ks < 4; ks++) {
      bf16x8 aq = *(const bf16x8*)&Qb[qrow][swz(qrow, kb * 8 + ks * 32)];
#pragma unroll
      for (int nj = 0; nj < 8; nj++) {
        const int krow = nj * 16 + lr;
        bf16x8 bk = *(const bf16x8*)&Kb[krow][swz(krow, kb * 8 + ks * 32)];
        s8[nj] = MFMA16(bk, aq, s8[nj]);   // D[k-token][q-token]
      }
    }
    // ---- per-lane softmax (xor 16, 32); P overwrites own Qb row ----
    {
      float m = s8[0][0];
#pragma unroll
      for (int nj = 0; nj < 8; nj++)
#pragma unroll
        for (int r = 0; r < 4; r++) m = fmaxf(m, s8[nj][r]);
      m = fmaxf(m, __shfl_xor(m, 16));
      m = fmaxf(m, __shfl_xor(m, 32));
      float sum = 0.f;
#pragma unroll
      for (int nj = 0; nj < 8; nj++)
#pragma unroll
        for (int r = 0; r < 4; r++) {
          s8[nj][r] = __expf((s8[nj][r] - m) * scale);
          sum += s8[nj][r];
        }
      sum += __shfl_xor(sum, 16);
      sum += __shfl_xor(sum, 32);
      const float inv = 1.f / sum;
#pragma unroll
      for (int nj = 0; nj < 8; nj++) {
        bf16x4 pp = {f2bf(s8[nj][0] * inv), f2bf(s8[nj][1] * inv),
                     f2bf(s8[nj][2] * inv), f2bf(s8[nj][3] * inv)};
        *(bf16x4*)&Qb[qrow][swz(qrow, nj * 16 + kb * 4)] = pp;
      }
    }

    // ---- O = P V : lane reads own P row (in-wave dep), all Vtb rows ----
    f32x4 o8[8];
#pragma unroll
    for (int i = 0; i < 8; i++) o8[i] = (f32x4){0.f, 0.f, 0.f, 0.f};
#pragma unroll
    for (int ks = 0; ks < 4; ks++) {
      bf16x8 bp = *(const bf16x8*)&Qb[qrow][swz(qrow, kb * 8 + ks * 32)];
#pragma unroll
      for (int mi = 0; mi < 8; mi++) {
        const int vrow = mi * 16 + lr;
        bf16x8 av = *(const bf16x8*)&Vtb[vrow][swz(vrow, kb * 8 + ks * 32)];
        o8[mi] = MFMA16(av, bp, o8[mi]);   // D[chan][q-token]
      }
    }

    // O overwrites own P row in Qb (all bp reads issued above; DS ops from a
    // wave complete in order -> no barrier needed; no other wave reads this
    // row between barriers B and D). This removes round-13's barrier C.
#pragma unroll
    for (int mi = 0; mi < 8; mi++) {
      const int cc = mi * 16 + kb * 4;
      bf16x4 po = {f2bf(o8[mi][0]), f2bf(o8[mi][1]), f2bf(o8[mi][2]), f2bf(o8[mi][3])};
      *(bf16x4*)&Qb[qrow][swz(qrow, cc)] = po;
    }

    __syncthreads();  // D: O complete for all waves

    // ---- proj: out-chans [wid*32, wid*32+32), all tokens; O from Qb ----
    {
      const short* w0 = woT + (size_t)(wid * 32 + lr) * 256 + h * 128 + kb * 8;
      const short* w1 = woT + (size_t)(wid * 32 + 16 + lr) * 256 + h * 128 + kb * 8;
      bf16x8 wa[4], wb2[4];
#pragma unroll
      for (int ks = 0; ks < 4; ks++) {
        wa[ks]  = *(const bf16x8*)(w0 + ks * 32);
        wb2[ks] = *(const bf16x8*)(w1 + ks * 32);
      }
#pragma unroll
      for (int nt = 0; nt < 8; nt++) {
        const int trow = nt * 16 + lr;
#pragma unroll
        for (int ks = 0; ks < 4; ks++) {
          bf16x8 bo = *(const bf16x8*)&Qb[trow][swz(trow, kb * 8 + ks * 32)];
          accp[0][nt] = MFMA16(wa[ks], bo, accp[0][nt]);
          accp[1][nt] = MFMA16(wb2[ks], bo, accp[1][nt]);
        }
      }
    }
  }

  // ---- accb write: token = nt*16+lr, outc = wid*32 + mi2*16 + kb*4 + r ----
#pragma unroll
  for (int mi2 = 0; mi2 < 2; mi2++) {
    const int outc = wid * 32 + mi2 * 16 + kb * 4;
    const float b0 = wob[outc], b1 = wob[outc + 1];
    const float b2 = wob[outc + 2], b3 = wob[outc + 3];
#pragma unroll
    for (int nt = 0; nt < 8; nt++) {
      const int token = tok0 + (nt * 16 + lr) * tstep;
      bf16x4 pv = {f2bf(accp[mi2][nt][0] + b0), f2bf(accp[mi2][nt][1] + b1),
                   f2bf(accp[mi2][nt][2] + b2), f2bf(accp[mi2][nt][3] + b3)};
      *(bf16x4*)(accb + (size_t)token * 256 + outc) = pv;
    }
  }
}

// ---- conv1x1: [relu(a0+a1)|xu|res] @ convT^T -> relu -> ytmp(bf16) + BN partials
__global__ __launch_bounds__(256) void k_gemm_conv(const short* __restrict__ accb0,
                                                   const short* __restrict__ accb1,
                                                   const short* __restrict__ xu,
                                                   const float* __restrict__ res,
                                                   const short* __restrict__ Bt,
                                                   short* __restrict__ ytmp,
                                                   float* __restrict__ partial) {
  __shared__ float redS[2][128], redS2[2][128];
  const int tid = threadIdx.x;
  const int lane = tid & 63, wid = tid >> 6;
  const int lr = lane & 15, kb = lane >> 4;
  const int wr = wid >> 1, wc = wid & 1;
  const int m0 = blockIdx.y * 128;
  f32x4 acc[4][4];
#pragma unroll
  for (int i = 0; i < 4; i++)
#pragma unroll
    for (int j = 0; j < 4; j++) acc[i][j] = (f32x4){0.f, 0.f, 0.f, 0.f};
  const short* arow0 = accb0 + (size_t)(m0 + wr * 64 + lr) * 256 + kb * 8;
  const short* arow1 = accb1 + (size_t)(m0 + wr * 64 + lr) * 256 + kb * 8;
  const short* arow2 = xu + (size_t)(m0 + wr * 64 + lr) * 256 + kb * 8;
  const short* brow = Bt + (size_t)(wc * 64 + lr) * 640 + kb * 8;
#pragma unroll
  for (int ks = 0; ks < 8; ks++) {
    bf16x8 a[4], b[4];
#pragma unroll
    for (int mi = 0; mi < 4; mi++) {
      bf16x8 t0 = *(const bf16x8*)(arow0 + (size_t)mi * 16 * 256 + ks * 32);
      bf16x8 t1 = *(const bf16x8*)(arow1 + (size_t)mi * 16 * 256 + ks * 32);
      bf16x8 tv;
#pragma unroll
      for (int u = 0; u < 8; u++) {
        float sv = bf2f(t0[u]) + bf2f(t1[u]);
        tv[u] = f2bf(fmaxf(sv, 0.f));
      }
      a[mi] = tv;
    }
#pragma unroll
    for (int nj = 0; nj < 4; nj++)
      b[nj] = *(const bf16x8*)(brow + (size_t)nj * 16 * 640 + ks * 32);
#pragma unroll
    for (int mi = 0; mi < 4; mi++)
#pragma unroll
      for (int nj = 0; nj < 4; nj++)
        acc[mi][nj] = MFMA16(a[mi], b[nj], acc[mi][nj]);
  }
#pragma unroll
  for (int ks = 8; ks < 16; ks++) {
    bf16x8 a[4], b[4];
#pragma unroll
    for (int mi = 0; mi < 4; mi++)
      a[mi] = *(const bf16x8*)(arow2 + (size_t)mi * 16 * 256 + (ks - 8) * 32);
#pragma unroll
    for (int nj = 0; nj < 4; nj++)
      b[nj] = *(const bf16x8*)(brow + (size_t)nj * 16 * 640 + ks * 32);
#pragma unroll
    for (int mi = 0; mi < 4; mi++)
#pragma unroll
      for (int nj = 0; nj < 4; nj++)
        acc[mi][nj] = MFMA16(a[mi], b[nj], acc[mi][nj]);
  }
  const int bC = (m0 >> 14) * 128;
  const int hh = (m0 >> 7) & 127;
#pragma unroll
  for (int ks = 16; ks < 20; ks++) {
    const int e0 = (ks - 16) * 32 + kb * 8;
    bf16x8 a[4], b[4];
#pragma unroll
    for (int mi = 0; mi < 4; mi++) {
      const int wl = wr * 64 + mi * 16 + lr;
      const float* rp = res + ((size_t)(bC + e0) * 128 + hh) * 128 + wl;
      bf16x8 tv;
#pragma unroll
      for (int u = 0; u < 8; u++) tv[u] = f2bf(rp[(size_t)u * 16384]);
      a[mi] = tv;
    }
#pragma unroll
    for (int nj = 0; nj < 4; nj++)
      b[nj] = *(const bf16x8*)(brow + (size_t)nj * 16 * 640 + ks * 32);
#pragma unroll
    for (int mi = 0; mi < 4; mi++)
#pragma unroll
      for (int nj = 0; nj < 4; nj++)
        acc[mi][nj] = MFMA16(a[mi], b[nj], acc[mi][nj]);
  }
  // epilogue: relu -> bf16 ytmp + per-channel partial sums (exact f32)
#pragma unroll
  for (int nj = 0; nj < 4; nj++) {
    float s = 0.f, s2 = 0.f;
    const int c = wc * 64 + nj * 16 + lr;
#pragma unroll
    for (int mi = 0; mi < 4; mi++) {
      const int rbase = m0 + wr * 64 + mi * 16 + kb * 4;
#pragma unroll
      for (int r = 0; r < 4; r++) {
        const float yv = fmaxf(acc[mi][nj][r], 0.f);
        ytmp[(size_t)(rbase + r) * 128 + c] = f2bf(yv);
        s += yv; s2 += yv * yv;
      }
    }
    s += __shfl_xor(s, 16);  s += __shfl_xor(s, 32);
    s2 += __shfl_xor(s2, 16); s2 += __shfl_xor(s2, 32);
    if (kb == 0) { redS[wr][c] = s; redS2[wr][c] = s2; }
  }
  __syncthreads();
  if (tid < 128) {
    partial[((size_t)blockIdx.y * 128 + tid) * 2]     = redS[0][tid] + redS[1][tid];
    partial[((size_t)blockIdx.y * 128 + tid) * 2 + 1] = redS2[0][tid] + redS2[1][tid];
  }
}

// ---------------- BN stats final reduce: one wave per channel ----------------
__global__ __launch_bounds__(64) void k_bnstats2(const float* __restrict__ partial,
                                                 float* __restrict__ stats) {
  const int ch = blockIdx.x;
  const int t = threadIdx.x;
  float s = 0.f, s2 = 0.f;
  for (int i = t; i < 512; i += 64) {
    s  += partial[(size_t)(i * 128 + ch) * 2];
    s2 += partial[(size_t)(i * 128 + ch) * 2 + 1];
  }
#pragma unroll
  for (int d = 1; d < 64; d <<= 1) {
    s  += __shfl_xor(s, d);
    s2 += __shfl_xor(s2, d);
  }
  if (t == 0) {
    const float mu = s * (1.f / 65536.f);
    const float var = s2 * (1.f / 65536.f) - mu * mu;   // biased
    stats[ch * 2] = mu;
    stats[ch * 2 + 1] = rsqrtf(var + 1e-5f);
  }
}

// ---------------- BN apply + transpose to (B,E,H,W), coalesced writes -------
__global__ __launch_bounds__(256) void k_bnout(const short* __restrict__ y,
                                               const float* __restrict__ stats,
                                               const float* __restrict__ gamma,
                                               const float* __restrict__ beta,
                                               float* __restrict__ out) {
  const int bh = blockIdx.x;
  const int b = bh >> 7, h = bh & 127;
  const int w = threadIdx.x & 127, half = threadIdx.x >> 7;
  const short* yp = y + (size_t)(bh * 128 + w) * 128 + half * 64;
  float* op = out + ((size_t)(b * 128) << 14) + h * 128 + w;
#pragma unroll
  for (int e8 = 0; e8 < 8; e8++) {
    bf16x8 v = *(const bf16x8*)(yp + e8 * 8);
#pragma unroll
    for (int u = 0; u < 8; u++) {
      const int e = half * 64 + e8 * 8 + u;
      const float mu = stats[e * 2], rstd = stats[e * 2 + 1];
      op[(size_t)e << 14] = (bf2f(v[u]) - mu) * rstd * gamma[e] + beta[e];
    }
  }
}

// ---------------- launcher ----------------
extern "C" void kernel_launch(void* const* d_in, const int* in_sizes, int n_in,
                              void* d_out, int out_size, void* d_ws, size_t ws_size,
                              hipStream_t stream) {
  const float* x      = (const float*)d_in[0];
  const float* res    = (const float*)d_in[1];
  const float* wq_h   = (const float*)d_in[2];
  const float* wkv_h  = (const float*)d_in[3];
  const float* wo_h   = (const float*)d_in[4];
  const float* wob_h  = (const float*)d_in[5];
  const float* wq_w   = (const float*)d_in[6];
  const float* wkv_w  = (const float*)d_in[7];
  const float* wo_w   = (const float*)d_in[8];
  const float* wob_w  = (const float*)d_in[9];
  const float* conv_w = (const float*)d_in[10];
  const float* gamma  = (const float*)d_in[11];
  const float* beta   = (const float*)d_in[12];

  char* ws = (char*)d_ws;
  short* wqkvT[2] = {(short*)(ws + 0), (short*)(ws + 393216)};
  short* woT[2]   = {(short*)(ws + 786432), (short*)(ws + 917504)};
  short* convT    = (short*)(ws + 1048576);
  short* xu       = (short*)(ws + 1245184);
  short* ytmp     = (short*)(ws + 34799616);
  float* partial  = (float*)(ws + 51576832);
  float* stats    = (float*)(ws + 52101120);
  short* accb1    = (short*)(ws + 52102144);
  short* accb0    = (short*)d_out;             // dir-0 axial output in d_out
  float* out      = (float*)d_out;

  if (ws_size < 85656576ull)
    fprintf(stderr, "kernel_launch: ws_size %zu too small\n", ws_size);

  // fused weight prep: starts 0,64,192,256,384,448,512; total 592 tiles
  WtAll P;
  P.src[0] = wq_h;  P.dst[0] = wqkvT[0];          P.K[0] = 256; P.N[0] = 256; P.tile0[0] = 0;
  P.src[1] = wkv_h; P.dst[1] = wqkvT[0] + 65536;  P.K[1] = 256; P.N[1] = 512; P.tile0[1] = 64;
  P.src[2] = wq_w;  P.dst[2] = wqkvT[1];          P.K[2] = 256; P.N[2] = 256; P.tile0[2] = 192;
  P.src[3] = wkv_w; P.dst[3] = wqkvT[1] + 65536;  P.K[3] = 256; P.N[3] = 512; P.tile0[3] = 256;
  P.src[4] = wo_h;  P.dst[4] = woT[0];            P.K[4] = 256; P.N[4] = 256; P.tile0[4] = 384;
  P.src[5] = wo_w;  P.dst[5] = woT[1];            P.K[5] = 256; P.N[5] = 256; P.tile0[5] = 448;
  P.src[6] = conv_w;P.dst[6] = convT;             P.K[6] = 640; P.N[6] = 128; P.tile0[6] = 512;
  k_wt_all<<<592, 256, 0, stream>>>(P);

  k_upsample<<<dim3(512, 4), 256, 0, stream>>>(x, xu);

  k_fused<<<dim3(512, 2), 512, 0, stream>>>(xu, wqkvT[0], woT[0],
                                            wob_h, wob_w, accb0, accb1);

  k_gemm_conv<<<dim3(1, 512), 256, 0, stream>>>(accb0, accb1, xu, res, convT,
                                                ytmp, partial);
  k_bnstats2<<<128, 64, 0, stream>>>(partial, stats);
  k_bnout<<<512, 256, 0, stream>>>(ytmp, stats, gamma, beta, out);
}